// Round 17
// baseline (141.581 us; speedup 1.0000x reference)
//
#include <hip/hip_runtime.h>

typedef unsigned char u8;
typedef unsigned short u16;
typedef u16 u16x4 __attribute__((ext_vector_type(4)));
typedef u16 u16x8 __attribute__((ext_vector_type(8)));
typedef __bf16 bf16x8 __attribute__((ext_vector_type(8)));
typedef float f32x2 __attribute__((ext_vector_type(2)));
typedef float f32x4 __attribute__((ext_vector_type(4)));
typedef long longx2 __attribute__((ext_vector_type(2)));

#define BB 16
#define TT 512
#define EE 768
#define HH 12
#define DD 64
#define LL 100
#define BT (BB*TT)             /* 8192 */
#define BTE ((size_t)BT*EE)    /* 6291456 */
#define LOG2E 1.44269504f
#define QSCALE (0.125f*LOG2E)  /* 1/sqrt(D)*log2e, folded into Q projection */
#define FIXMAX 44.0f           /* fixed softmax shift (log2 domain) */
#define PSTR 76                /* Pl row stride (u16): bank=(6*l15+4g)%32, <=2-way */

__device__ __forceinline__ float bf2f(u16 u){
  union { float f; unsigned int i; } v; v.i = ((unsigned int)u) << 16; return v.f;
}
__device__ __forceinline__ u16 f2bf(float f){
  __bf16 h = (__bf16)f;
  union { __bf16 h; u16 u; } v; v.h = h; return v.u;
}
// fp8 e4m3 (OCP on gfx950) pack/unpack via HW cvt
__device__ __forceinline__ u16 pk_fp8(float a, float b){
  return (u16)(__builtin_amdgcn_cvt_pk_fp8_f32(a, b, 0, false) & 0xffff);
}
__device__ __forceinline__ u8 f2fp8(float a){
  return (u8)(__builtin_amdgcn_cvt_pk_fp8_f32(a, 0.f, 0, false) & 0xff);
}

// async 16B global->LDS DMA. LDS dest = wave-uniform base + lane*16.
__device__ __forceinline__ void gload16(const void* g, void* l){
  __builtin_amdgcn_global_load_lds(
      (const __attribute__((address_space(1))) void*)g,
      (__attribute__((address_space(3))) void*)l, 16, 0, 0);
}

// ---------------------------------------------------------------------------
// Merged prep: blocks 0-575 transpose+cast W[4] into FP8 [N][K];
// blocks 576-959 build TEb[128][768] / TEt[768][128] bf16; 960-991 mask bias.
// ---------------------------------------------------------------------------
__global__ __launch_bounds__(256,1) void prep_all_kernel(
    const float* __restrict__ Wq, const float* __restrict__ Wk,
    const float* __restrict__ Wv, const float* __restrict__ Wo,
    u8* __restrict__ WT8,
    const float* __restrict__ TE, u16* __restrict__ TEb, u16* __restrict__ TEt,
    const float* __restrict__ mask, float* __restrict__ MBg)
{
  __shared__ float tile[64][65];
  int bx = blockIdx.x;
  int tid = threadIdx.x;
  if (bx < 576){
    int m  = bx / 144, t = bx % 144;
    int tr = t / 12,  tc = t % 12;
    const float* W = (m==0)?Wq : (m==1)?Wk : (m==2)?Wv : Wo;
    u8* dst = WT8 + (size_t)m * EE * EE;
#pragma unroll
    for (int i=0;i<16;i++){
      int idx = tid + 256*i; int r = idx>>6, c = idx&63;
      tile[r][c] = W[(size_t)(tr*64+r)*EE + tc*64 + c];
    }
    __syncthreads();
    // dst[n][k] = W[k][n] in fp8, packed pairs along k
#pragma unroll
    for (int i=0;i<8;i++){
      int idx = tid + 256*i;          // 2048 = 64 r x 32 col-pairs
      int r = idx >> 5, cp = idx & 31;
      u16 pk = pk_fp8(tile[cp*2][r], tile[cp*2+1][r]);
      *(u16*)&dst[(size_t)(tc*64+r)*EE + tr*64 + cp*2] = pk;
    }
  } else if (bx < 960){
    int e = (bx - 576)*2 + (tid >> 7);
    int c = tid & 127;
    u16 v = 0;
    if (c < LL) v = f2bf(TE[(size_t)c*EE + e]);
    TEt[(size_t)e*128 + c] = v;
    if (e < 128){
#pragma unroll
      for (int k=c; k<EE; k+=128)
        TEb[(size_t)e*EE + k] = (e < LL) ? f2bf(TE[(size_t)e*EE + k]) : (u16)0;
    }
  } else {
    int i = (bx - 960)*256 + tid;
    MBg[i] = (1.0f - mask[i]) * (-1e9f * LOG2E) - FIXMAX;
  }
}

// ---------------------------------------------------------------------------
// K1 v2: label scores + softmax, LDS-free (unchanged).
// ---------------------------------------------------------------------------
__global__ __launch_bounds__(64) void label_scores_kernel(
    const float* __restrict__ X, const u16* __restrict__ TEb,
    float* __restrict__ scores_out, u16* __restrict__ att)
{
  int m0 = blockIdx.x * 16;
  int lane = threadIdx.x;
  int l15 = lane & 15, g = lane >> 4;

  const float* xrow = X + (size_t)(m0 + l15)*EE;
  f32x4 s[7] = {};
  for (int k0=0; k0<EE; k0+=64){
    bf16x8 af[2];
#pragma unroll
    for (int kk=0;kk<2;kk++){
      const float* src = xrow + k0 + kk*32 + g*8;
      float4 a = *(const float4*)src, b = *(const float4*)(src+4);
      bf16x8 o;
      o[0]=(__bf16)a.x; o[1]=(__bf16)a.y; o[2]=(__bf16)a.z; o[3]=(__bf16)a.w;
      o[4]=(__bf16)b.x; o[5]=(__bf16)b.y; o[6]=(__bf16)b.z; o[7]=(__bf16)b.w;
      af[kk] = o;
    }
#pragma unroll
    for (int nt=0;nt<7;nt++){
      bf16x8 b0 = *(const bf16x8*)&TEb[(size_t)(nt*16+l15)*EE + k0 + g*8];
      bf16x8 b1 = *(const bf16x8*)&TEb[(size_t)(nt*16+l15)*EE + k0 + 32 + g*8];
      s[nt] = __builtin_amdgcn_mfma_f32_16x16x32_bf16(af[0], b0, s[nt], 0,0,0);
      s[nt] = __builtin_amdgcn_mfma_f32_16x16x32_bf16(af[1], b1, s[nt], 0,0,0);
    }
  }

  int rowb = m0 + g*4;
#pragma unroll
  for (int nt=0;nt<7;nt++){
    int col = nt*16 + l15;
    if (col < LL){
#pragma unroll
      for (int r=0;r<4;r++)
        scores_out[(size_t)(rowb + r)*LL + col] = s[nt][r];
    }
  }
  if (l15 >= 4){
#pragma unroll
    for (int r=0;r<4;r++) s[6][r] = -1e30f;
  }
  float inv[4];
#pragma unroll
  for (int r=0;r<4;r++){
    float tm = s[0][r];
#pragma unroll
    for (int nt=1;nt<7;nt++) tm = fmaxf(tm, s[nt][r]);
    tm = fmaxf(tm, __shfl_xor(tm, 1, 16));
    tm = fmaxf(tm, __shfl_xor(tm, 2, 16));
    tm = fmaxf(tm, __shfl_xor(tm, 4, 16));
    tm = fmaxf(tm, __shfl_xor(tm, 8, 16));
    float ps = 0.f;
#pragma unroll
    for (int nt=0;nt<7;nt++){
      float p = exp2f((s[nt][r] - tm) * LOG2E);
      s[nt][r] = p; ps += p;
    }
    ps += __shfl_xor(ps, 1, 16);
    ps += __shfl_xor(ps, 2, 16);
    ps += __shfl_xor(ps, 4, 16);
    ps += __shfl_xor(ps, 8, 16);
    inv[r] = 1.f/ps;
  }
#pragma unroll
  for (int nt=0;nt<7;nt++){
    int col = nt*16 + l15;
#pragma unroll
    for (int r=0;r<4;r++)
      att[(size_t)(rowb + r)*128 + col] = f2bf(s[nt][r] * inv[r]);
  }
  {
    int col = 112 + l15;
#pragma unroll
    for (int r=0;r<4;r++) att[(size_t)(rowb + r)*128 + col] = 0;
  }
}

// ---------------------------------------------------------------------------
// fle GEMM (bf16 interior, K=128): HT8 = fp8(X+acc), HU8 = fp8(X+tp).
// ---------------------------------------------------------------------------
__global__ __launch_bounds__(256,1) void gemm_fle_kernel(
    const u16* __restrict__ A, const u16* __restrict__ BTw,
    const float* __restrict__ Xf, const float* __restrict__ tp,
    u8* __restrict__ HT8, u8* __restrict__ HU8, int N, int K)
{
  __shared__ u16 As[128*40];
  __shared__ u16 Bs[128*40];
  int nb = N >> 7;
  int m0 = (blockIdx.x / nb) << 7;
  int n0 = (blockIdx.x % nb) << 7;
  int tid  = threadIdx.x, lane = tid & 63, w = tid >> 6;
  int wm = (w >> 1) << 6, wn = (w & 1) << 6;
  int lr = lane & 15, lk = (lane >> 4) << 3;

  f32x4 acc[4][4] = {};

  for (int k0 = 0; k0 < K; k0 += 32){
    __syncthreads();
#pragma unroll
    for (int i=0;i<2;i++){
      int idx = tid + (i<<8);
      int row = idx >> 2, kq = (idx & 3) << 3;
      *(u16x8*)&As[row*40 + kq] = *(const u16x8*)&A  [(size_t)(m0+row)*K + k0 + kq];
      *(u16x8*)&Bs[row*40 + kq] = *(const u16x8*)&BTw[(size_t)(n0+row)*K + k0 + kq];
    }
    __syncthreads();
    bf16x8 af[4], bfr[4];
#pragma unroll
    for (int i=0;i<4;i++) af [i] = *(const bf16x8*)&As[(wm + i*16 + lr)*40 + lk];
#pragma unroll
    for (int j=0;j<4;j++) bfr[j] = *(const bf16x8*)&Bs[(wn + j*16 + lr)*40 + lk];
#pragma unroll
    for (int i=0;i<4;i++)
#pragma unroll
      for (int j=0;j<4;j++)
        acc[i][j] = __builtin_amdgcn_mfma_f32_16x16x32_bf16(af[i], bfr[j], acc[i][j], 0, 0, 0);
  }

  int rbase = (lane >> 4) << 2;
#pragma unroll
  for (int j=0;j<4;j++){
    int col = n0 + wn + j*16 + lr;
    float tpv = tp[col];
#pragma unroll
    for (int i=0;i<4;i++){
#pragma unroll
      for (int r=0;r<4;r++){
        int row = m0 + wm + i*16 + rbase + r;
        float x = Xf[(size_t)row*EE + col];
        HT8[(size_t)row*EE + col] = f2fp8(x + acc[i][j][r]);
        HU8[(size_t)row*EE + col] = f2fp8(x + tpv);
      }
    }
  }
}

// ---------------------------------------------------------------------------
// gemm8 v4: FP8 projection GEMM (unchanged from R16: frozen R13 k-loop +
// LDS-staged 64B-contiguous store epilogue).
// ---------------------------------------------------------------------------
template<int NB, int FUSED>
__global__ __launch_bounds__(256,2) void gemm8_kernel(
    const u8* __restrict__ A0, const u8* __restrict__ A1,
    const u8* __restrict__ Wb,
    const float* __restrict__ b0, const float* __restrict__ b1,
    const float* __restrict__ b2,
    u16* __restrict__ C0, u16* __restrict__ C1, u16* __restrict__ C2)
{
  __shared__ __align__(16) u8 smem[33792];   // max(As+Bs=32KB, Cs=33792B)
  u8* As = smem;
  u8* Bs = smem + 16384;
  u16* Cs = (u16*)smem;                      // [128][132] bf16
  const int K = EE;   // bytes per row (1B/elt)

  int nwg = gridDim.x;
  int bid = blockIdx.x;
  int cpx = nwg >> 3;
  int swz = (bid & 7) * cpx + (bid >> 3);
  int mb = swz / NB, nb = swz % NB;
  int m0 = mb << 7;
  int n0 = (FUSED ? (nb % 6) : nb) << 7;

  int which = FUSED ? (nb / 6) : 0;
  const u8* Ap; const u8* Wp; const float* bp; u16* Cp;
  if (!FUSED){ Ap = A0; Wp = Wb; bp = b0; Cp = C0; }
  else {
    if (which == 0){ Ap = A0; Wp = Wb;                      bp = b0; Cp = C0; }
    else if (which == 1){ Ap = A1; Wp = Wb + (size_t)EE*EE; bp = b1; Cp = C1; }
    else { Ap = A1; Wp = Wb + 2*(size_t)EE*EE;              bp = b2; Cp = C2; }
  }

  int tid = threadIdx.x, lane = tid & 63, w = tid >> 6;
  int wm = (w >> 1) << 6, wn = (w & 1) << 6;
  int lr = lane & 15, g = lane >> 4;
  int lrow = lane >> 3;
  int lchunk = (lane & 7) ^ lrow;          // source pre-swizzle (rule #21)

  f32x4 acc[4][4] = {};

  for (int k0 = 0; k0 < K; k0 += 128){
    __syncthreads();
#pragma unroll
    for (int t=0;t<4;t++){
      int r0 = w*32 + t*8;
      gload16(&Ap[(size_t)(m0 + r0 + lrow)*K + k0 + (lchunk<<4)], &As[r0*128]);
      gload16(&Wp[(size_t)(n0 + r0 + lrow)*K + k0 + (lchunk<<4)], &Bs[r0*128]);
    }
    __syncthreads();
#pragma unroll
    for (int t=0;t<2;t++){
      int cs = ((t<<2) + g) ^ (lr & 7);    // 16B chunk; zero-conflict pattern
      longx2 af[4], bfr[4];
#pragma unroll
      for (int i=0;i<4;i++) af [i] = *(const longx2*)&As[(wm + i*16 + lr)*128 + (cs<<4)];
#pragma unroll
      for (int j=0;j<4;j++) bfr[j] = *(const longx2*)&Bs[(wn + j*16 + lr)*128 + (cs<<4)];
#pragma unroll
      for (int i=0;i<4;i++)
#pragma unroll
        for (int j=0;j<4;j++){
          acc[i][j] = __builtin_amdgcn_mfma_f32_16x16x32_fp8_fp8(af[i][0], bfr[j][0], acc[i][j], 0, 0, 0);
          acc[i][j] = __builtin_amdgcn_mfma_f32_16x16x32_fp8_fp8(af[i][1], bfr[j][1], acc[i][j], 0, 0, 0);
        }
    }
  }

  // ---- epilogue via LDS: Cs[row][col], stride 132 ----
  int rbase = (lane >> 4) << 2;
  float scq = (FUSED && which==0) ? QSCALE : 1.0f;
  __syncthreads();                         // all As/Bs reads complete
#pragma unroll
  for (int j=0;j<4;j++){
    int col = wn + j*16 + lr;
    float bv = bp[n0 + col];
#pragma unroll
    for (int i=0;i<4;i++)
#pragma unroll
      for (int r=0;r<4;r++)
        Cs[(wm + i*16 + rbase + r)*132 + col] = f2bf((acc[i][j][r] + bv) * scq);
  }
  __syncthreads();

  if (FUSED && which == 2){
    // V transposed: VT[(bb*HH+hh)*DD+d][t]. 4 lanes cover 64B contiguous t.
    int bb = m0 >> 9, t0 = m0 & 511;
    int colb = tid >> 2;                   // 0..63
    int tq = (tid & 3) << 3;               // 0,8,16,24
#pragma unroll
    for (int c2=0;c2<2;c2++){
      int col = colb + (c2<<6);            // 0..127
      int hh = (n0 + col) >> 6, d = (n0 + col) & 63;
      u16* dst = &Cp[((size_t)(bb*HH + hh)*DD + d)*TT + t0];
#pragma unroll
      for (int s=0;s<4;s++){
        int tt = tq + (s<<5);
        u16x8 v;
#pragma unroll
        for (int e=0;e<8;e++) v[e] = Cs[(tt+e)*132 + col];
        *(u16x8*)&dst[tt] = v;
      }
    }
  } else {
    // Q/K/O row-major: 4 lanes x 16B = 64B contiguous per quad.
#pragma unroll
    for (int p=0;p<2;p++){
      int row = (tid >> 2) + (p<<6);       // 0..127
      int c0 = (tid & 3) << 3;             // 0,8,16,24
      size_t gbase = (size_t)(m0 + row)*EE + n0;
      const u16* src = &Cs[row*132];
#pragma unroll
      for (int s=0;s<4;s++){
        int c = c0 + (s<<5);
        u16x4 lo = *(const u16x4*)&src[c];
        u16x4 hi = *(const u16x4*)&src[c+4];
        u16x8 v;
#pragma unroll
        for (int e=0;e<4;e++){ v[e] = lo[e]; v[e+4] = hi[e]; }
        *(u16x8*)&Cp[gbase + c] = v;
      }
    }
  }
}

// ---------------------------------------------------------------------------
// K4: MFMA flash attention v5 — fixed-max softmax. CHANGES vs R16:
//  (1) SINGLE-buffer K/V + 2-barrier loop (proven gemm2 shape): LDS 51.2 ->
//      35.8 KB => 4 blocks/CU (16 waves/CU, was 3). Session evidence
//      (R6/R9/R10/R14 + m114): inter-block overlap beats dbuf prefetch.
//  (2) Pl row stride 72 -> 76 u16: old stride gave bank start 4*(l15+g)%32
//      on the pa b128 re-reads = 8-way conflict (the 737K counter); stride 76
//      gives (6*l15+4g)%32 = max 2-way (free). P-writes stay <=2-way.
// ---------------------------------------------------------------------------
__global__ __launch_bounds__(256,4) void attn_mfma_kernel(
    const u16* __restrict__ Q, const u16* __restrict__ K,
    const u16* __restrict__ VT, const float* __restrict__ MBg,
    u8* __restrict__ CTX8)
{
  __shared__ u16 Ks [64*64];
  __shared__ u16 VTs[64*64];
  __shared__ u16 Pl [4][32*PSTR];

  int bx = blockIdx.x;
  int bh = bx % (BB*HH), q0 = (bx / (BB*HH)) << 7;
  int b = bh / HH, h = bh % HH;
  int tid = threadIdx.x, lane = tid & 63, w = tid >> 6;
  int l15 = lane & 15, g = lane >> 4;
  int wq0 = q0 + w*32;
  size_t rowbase = (size_t)b*TT;
  u16* pw = &Pl[w][0];
  const u16* Kbh = K  + rowbase*EE + h*DD;
  const u16* Vbh = VT + (size_t)bh*DD*TT;
  int lrow = lane >> 3, lchunk = (lane & 7) ^ (lane >> 3);

  bf16x8 qf[2][2];
#pragma unroll
  for (int i=0;i<2;i++)
#pragma unroll
    for (int kk=0;kk<2;kk++)
      qf[i][kk] = *(const bf16x8*)&Q[(rowbase + wq0 + i*16 + l15)*EE + h*DD + kk*32 + g*8];

  f32x4 ctxf[2][4] = {};
  float lrun[2][4] = {};

  for (int kt=0; kt<8; ++kt){
    int k0 = kt << 6;

    // mb loads first (independent of LDS; land during staging wait)
    float mb[4];
#pragma unroll
    for (int kb=0;kb<4;kb++) mb[kb] = MBg[rowbase + k0 + kb*16 + l15];

    // stage K + VT tiles (single buffer)
#pragma unroll
    for (int it=0; it<2; ++it){
      int r0 = w*16 + it*8;
      gload16(&Kbh[(size_t)(k0 + r0 + lrow)*EE + (lchunk<<3)], &Ks [r0*64]);
      gload16(&Vbh[(size_t)(r0 + lrow)*TT + k0 + (lchunk<<3)], &VTs[r0*64]);
    }
    __syncthreads();                       // DMA landed

    // ---- S = Q K^T (log2e domain; Q pre-scaled) ----
    f32x4 s[2][4] = {};
#pragma unroll
    for (int kk=0;kk<2;kk++){
      int cs = ((kk<<2) + g) ^ (l15 & 7);
      bf16x8 kf[4];
#pragma unroll
      for (int kb=0;kb<4;kb++)
        kf[kb] = *(const bf16x8*)&Ks[(kb*16 + l15)*64 + (cs<<3)];
#pragma unroll
      for (int i=0;i<2;i++)
#pragma unroll
        for (int kb=0;kb<4;kb++)
          s[i][kb] = __builtin_amdgcn_mfma_f32_16x16x32_bf16(qf[i][kk], kf[kb], s[i][kb], 0,0,0);
    }

    // ---- diag mask ----
    if ((k0 < wq0 + 32) && (k0 + 64 > wq0)){
#pragma unroll
      for (int i=0;i<2;i++){
        int qr = wq0 + i*16 + g*4;
#pragma unroll
        for (int kb=0;kb<4;kb++){
          int kpos = k0 + kb*16 + l15;
#pragma unroll
          for (int r=0;r<4;r++)
            if (kpos == qr + r) s[i][kb][r] -= 1e9f*LOG2E;
        }
      }
    }

    // ---- p = exp2(s + mb); lane-local sum; P -> LDS (A-frag layout) ----
#pragma unroll
    for (int i=0;i<2;i++)
#pragma unroll
      for (int kb=0;kb<4;kb++)
#pragma unroll
        for (int r=0;r<4;r++){
          float p = exp2f(s[i][kb][r] + mb[kb]);
          lrun[i][r] += p;
          pw[(i*16 + g*4 + r)*PSTR + kb*16 + l15] = f2bf(p);
        }

    bf16x8 pa[2][2];
#pragma unroll
    for (int i=0;i<2;i++)
#pragma unroll
      for (int kk=0;kk<2;kk++)
        pa[i][kk] = *(const bf16x8*)&pw[(i*16 + l15)*PSTR + kk*32 + g*8];

    // ---- ctx += P V ----
#pragma unroll
    for (int kk=0;kk<2;kk++){
      int cs = ((kk<<2) + g) ^ (l15 & 7);
      bf16x8 vf[4];
#pragma unroll
      for (int dj=0;dj<4;dj++)
        vf[dj] = *(const bf16x8*)&VTs[(dj*16 + l15)*64 + (cs<<3)];
#pragma unroll
      for (int i=0;i<2;i++)
#pragma unroll
        for (int dj=0;dj<4;dj++)
          ctxf[i][dj] = __builtin_amdgcn_mfma_f32_16x16x32_bf16(pa[i][kk], vf[dj], ctxf[i][dj], 0,0,0);
    }
    __syncthreads();                       // all reads done before next stage
  }

  float inv[2][4];
#pragma unroll
  for (int i=0;i<2;i++)
#pragma unroll
    for (int r=0;r<4;r++){
      float l = lrun[i][r];
      l += __shfl_xor(l, 1, 16);
      l += __shfl_xor(l, 2, 16);
      l += __shfl_xor(l, 4, 16);
      l += __shfl_xor(l, 8, 16);
      inv[i][r] = 1.0f / l;
    }
#pragma unroll
  for (int i=0;i<2;i++)
#pragma unroll
    for (int dj=0;dj<4;dj++)
#pragma unroll
      for (int r=0;r<4;r++)
        pw[(i*16 + g*4 + r)*64 + dj*16 + l15] = f2bf(ctxf[i][dj][r] * inv[i][r]);
#pragma unroll
  for (int t=0;t<4;t++){
    int row = lane >> 1, c = ((lane & 1)<<5) + t*8;
    const u16* pv = &pw[row*64 + c];
    u16x4 o8;
#pragma unroll
    for (int e=0;e<4;e++) o8[e] = pk_fp8(bf2f(pv[2*e]), bf2f(pv[2*e+1]));
    *(u16x4*)&CTX8[(rowbase + wq0 + row)*EE + h*DD + c] = o8;
  }
}

// ---------------------------------------------------------------------------
// K5: LayerNorm(AO + HU)*g + b + HT -> out (f32). HU/HT read as fp8.
// ---------------------------------------------------------------------------
__global__ __launch_bounds__(192,1) void ln_out_kernel(
    const u16* __restrict__ AO, const u8* __restrict__ HU8,
    const u8* __restrict__ HT8, const float* __restrict__ g,
    const float* __restrict__ bta, float* __restrict__ out)
{
  __shared__ float red[3];
  int r = blockIdx.x, tid = threadIdx.x;
  size_t base = (size_t)r*EE;
  int e0 = tid*4;
  u16x4 ao = *(const u16x4*)&AO[base+e0];
  int hu4 = *(const int*)&HU8[base+e0];
  int ht4 = *(const int*)&HT8[base+e0];
  f32x2 hulo = __builtin_amdgcn_cvt_pk_f32_fp8(hu4, false);
  f32x2 huhi = __builtin_amdgcn_cvt_pk_f32_fp8(hu4, true);
  f32x2 htlo = __builtin_amdgcn_cvt_pk_f32_fp8(ht4, false);
  f32x2 hthi = __builtin_amdgcn_cvt_pk_f32_fp8(ht4, true);
  float huv[4] = {hulo[0], hulo[1], huhi[0], huhi[1]};
  float htv[4] = {htlo[0], htlo[1], hthi[0], hthi[1]};
  float x[4];
#pragma unroll
  for (int j=0;j<4;j++) x[j] = bf2f(ao[j]) + huv[j];

  float s = x[0]+x[1]+x[2]+x[3];
#pragma unroll
  for (int o=32;o;o>>=1) s += __shfl_xor(s, o, 64);
  int w = tid>>6;
  if ((tid&63)==0) red[w] = s;
  __syncthreads();
  float mu = (red[0]+red[1]+red[2]) * (1.0f/EE);
  __syncthreads();
  float d2 = 0.f;
#pragma unroll
  for (int j=0;j<4;j++){ float d = x[j]-mu; d2 += d*d; }
#pragma unroll
  for (int o=32;o;o>>=1) d2 += __shfl_xor(d2, o, 64);
  if ((tid&63)==0) red[w] = d2;
  __syncthreads();
  float var = (red[0]+red[1]+red[2]) * (1.0f/EE);
  float rs = rsqrtf(var + 1e-12f);
  float4 gg = *(const float4*)&g[e0];
  float4 bb = *(const float4*)&bta[e0];
  float4 o4;
  o4.x = (x[0]-mu)*rs*gg.x + bb.x + htv[0];
  o4.y = (x[1]-mu)*rs*gg.y + bb.y + htv[1];
  o4.z = (x[2]-mu)*rs*gg.z + bb.z + htv[2];
  o4.w = (x[3]-mu)*rs*gg.w + bb.w + htv[3];
  *(float4*)&out[base+e0] = o4;
}

// ---------------------------------------------------------------------------
extern "C" void kernel_launch(void* const* d_in, const int* in_sizes, int n_in,
                              void* d_out, int out_size, void* d_ws, size_t ws_size,
                              hipStream_t stream)
{
  (void)in_sizes; (void)n_in; (void)out_size; (void)ws_size;
  const float* X    = (const float*)d_in[0];
  const float* mask = (const float*)d_in[1];
  const float* TE   = (const float*)d_in[2];
  const float* tp   = (const float*)d_in[3];
  const float* Wq   = (const float*)d_in[4];
  const float* bq   = (const float*)d_in[5];
  const float* Wk   = (const float*)d_in[6];
  const float* bk   = (const float*)d_in[7];
  const float* Wv   = (const float*)d_in[8];
  const float* bv   = (const float*)d_in[9];
  const float* Wo   = (const float*)d_in[10];
  const float* bo   = (const float*)d_in[11];
  const float* ln_g = (const float*)d_in[12];
  const float* ln_b = (const float*)d_in[13];

  float* out    = (float*)d_out;
  float* scores = out + BTE;

  char* p = (char*)d_ws;
  u8*  HT8  = (u8*)p;  p += BTE;                 // fp8 [8192][768]
  u8*  HU8  = (u8*)p;  p += BTE;
  u8*  CTX8 = (u8*)p;  p += BTE;
  u8*  WT8  = (u8*)p;  p += (size_t)4*EE*EE;     // fp8 4x[768][768] transposed
  u16* Qb   = (u16*)p; p += BTE*2;               // bf16
  u16* Kb   = (u16*)p; p += BTE*2;
  u16* VTb  = (u16*)p; p += BTE*2;               // bf16 [bh*64+d][512]
  u16* AOb  = (u16*)p; p += BTE*2;
  u16* ATT  = (u16*)p; p += (size_t)BT*128*2;    // bf16 [8192][128]
  u16* TEb  = (u16*)p; p += (size_t)128*EE*2;
  u16* TEt  = (u16*)p; p += (size_t)EE*128*2;
  float* MBg = (float*)p;

  prep_all_kernel<<<dim3(992), dim3(256), 0, stream>>>(
      Wq, Wk, Wv, Wo, WT8, TE, TEb, TEt, mask, MBg);

  label_scores_kernel<<<dim3(BT/16), dim3(64), 0, stream>>>(X, TEb, scores, ATT);

  // fle GEMM + fused fp8 HT/HU epilogue: M=8192, N=768, K=128
  gemm_fle_kernel<<<dim3((BT/128)*(EE/128)), dim3(256), 0, stream>>>(
      ATT, TEt, X, tp, HT8, HU8, EE, 128);

  // fused QKV projections (fp8 inputs, bf16 outputs): 64 m x 18 n
  gemm8_kernel<18,1><<<dim3(64*18), dim3(256), 0, stream>>>(
      HU8, HT8, WT8, bq, bk, bv, Qb, Kb, VTb);

  attn_mfma_kernel<<<dim3(BB*HH*4), dim3(256), 0, stream>>>(Qb, Kb, VTb, MBg, CTX8);

  // O projection (fp8 inputs): 64 x 6
  gemm8_kernel<6,0><<<dim3(64*6), dim3(256), 0, stream>>>(
      CTX8, nullptr, WT8 + 3*(size_t)EE*EE, bo, nullptr, nullptr, AOb, nullptr, nullptr);

  ln_out_kernel<<<dim3(BT), dim3(192), 0, stream>>>(AOb, HU8, HT8, ln_g, ln_b, out);
}

// Round 18
// 121.678 us; speedup vs baseline: 1.1636x; 1.1636x over previous
//
#include <hip/hip_runtime.h>

typedef unsigned char u8;
typedef unsigned short u16;
typedef u16 u16x4 __attribute__((ext_vector_type(4)));
typedef u16 u16x8 __attribute__((ext_vector_type(8)));
typedef __bf16 bf16x8 __attribute__((ext_vector_type(8)));
typedef float f32x2 __attribute__((ext_vector_type(2)));
typedef float f32x4 __attribute__((ext_vector_type(4)));
typedef long longx2 __attribute__((ext_vector_type(2)));

#define BB 16
#define TT 512
#define EE 768
#define HH 12
#define DD 64
#define LL 100
#define BT (BB*TT)             /* 8192 */
#define BTE ((size_t)BT*EE)    /* 6291456 */
#define LOG2E 1.44269504f
#define QSCALE (0.125f*LOG2E)  /* 1/sqrt(D)*log2e, folded into Q projection */
#define FIXMAX 44.0f           /* fixed softmax shift (log2 domain) */
#define PSTR 76                /* Pl row stride (u16): pa-read banks (6*l15+4g)%32, <=2-way (was 8-way at 72) */

__device__ __forceinline__ float bf2f(u16 u){
  union { float f; unsigned int i; } v; v.i = ((unsigned int)u) << 16; return v.f;
}
__device__ __forceinline__ u16 f2bf(float f){
  __bf16 h = (__bf16)f;
  union { __bf16 h; u16 u; } v; v.h = h; return v.u;
}
// fp8 e4m3 (OCP on gfx950) pack/unpack via HW cvt
__device__ __forceinline__ u16 pk_fp8(float a, float b){
  return (u16)(__builtin_amdgcn_cvt_pk_fp8_f32(a, b, 0, false) & 0xffff);
}
__device__ __forceinline__ u8 f2fp8(float a){
  return (u8)(__builtin_amdgcn_cvt_pk_fp8_f32(a, 0.f, 0, false) & 0xff);
}

// async 16B global->LDS DMA. LDS dest = wave-uniform base + lane*16.
__device__ __forceinline__ void gload16(const void* g, void* l){
  __builtin_amdgcn_global_load_lds(
      (const __attribute__((address_space(1))) void*)g,
      (__attribute__((address_space(3))) void*)l, 16, 0, 0);
}

// ---------------------------------------------------------------------------
// Merged prep: blocks 0-575 transpose+cast W[4] into FP8 [N][K];
// blocks 576-959 build TEb[128][768] / TEt[768][128] bf16; 960-991 mask bias.
// ---------------------------------------------------------------------------
__global__ __launch_bounds__(256,1) void prep_all_kernel(
    const float* __restrict__ Wq, const float* __restrict__ Wk,
    const float* __restrict__ Wv, const float* __restrict__ Wo,
    u8* __restrict__ WT8,
    const float* __restrict__ TE, u16* __restrict__ TEb, u16* __restrict__ TEt,
    const float* __restrict__ mask, float* __restrict__ MBg)
{
  __shared__ float tile[64][65];
  int bx = blockIdx.x;
  int tid = threadIdx.x;
  if (bx < 576){
    int m  = bx / 144, t = bx % 144;
    int tr = t / 12,  tc = t % 12;
    const float* W = (m==0)?Wq : (m==1)?Wk : (m==2)?Wv : Wo;
    u8* dst = WT8 + (size_t)m * EE * EE;
#pragma unroll
    for (int i=0;i<16;i++){
      int idx = tid + 256*i; int r = idx>>6, c = idx&63;
      tile[r][c] = W[(size_t)(tr*64+r)*EE + tc*64 + c];
    }
    __syncthreads();
    // dst[n][k] = W[k][n] in fp8, packed pairs along k
#pragma unroll
    for (int i=0;i<8;i++){
      int idx = tid + 256*i;          // 2048 = 64 r x 32 col-pairs
      int r = idx >> 5, cp = idx & 31;
      u16 pk = pk_fp8(tile[cp*2][r], tile[cp*2+1][r]);
      *(u16*)&dst[(size_t)(tc*64+r)*EE + tr*64 + cp*2] = pk;
    }
  } else if (bx < 960){
    int e = (bx - 576)*2 + (tid >> 7);
    int c = tid & 127;
    u16 v = 0;
    if (c < LL) v = f2bf(TE[(size_t)c*EE + e]);
    TEt[(size_t)e*128 + c] = v;
    if (e < 128){
#pragma unroll
      for (int k=c; k<EE; k+=128)
        TEb[(size_t)e*EE + k] = (e < LL) ? f2bf(TE[(size_t)e*EE + k]) : (u16)0;
    }
  } else {
    int i = (bx - 960)*256 + tid;
    MBg[i] = (1.0f - mask[i]) * (-1e9f * LOG2E) - FIXMAX;
  }
}

// ---------------------------------------------------------------------------
// K1 v2: label scores + softmax, LDS-free (unchanged).
// ---------------------------------------------------------------------------
__global__ __launch_bounds__(64) void label_scores_kernel(
    const float* __restrict__ X, const u16* __restrict__ TEb,
    float* __restrict__ scores_out, u16* __restrict__ att)
{
  int m0 = blockIdx.x * 16;
  int lane = threadIdx.x;
  int l15 = lane & 15, g = lane >> 4;

  const float* xrow = X + (size_t)(m0 + l15)*EE;
  f32x4 s[7] = {};
  for (int k0=0; k0<EE; k0+=64){
    bf16x8 af[2];
#pragma unroll
    for (int kk=0;kk<2;kk++){
      const float* src = xrow + k0 + kk*32 + g*8;
      float4 a = *(const float4*)src, b = *(const float4*)(src+4);
      bf16x8 o;
      o[0]=(__bf16)a.x; o[1]=(__bf16)a.y; o[2]=(__bf16)a.z; o[3]=(__bf16)a.w;
      o[4]=(__bf16)b.x; o[5]=(__bf16)b.y; o[6]=(__bf16)b.z; o[7]=(__bf16)b.w;
      af[kk] = o;
    }
#pragma unroll
    for (int nt=0;nt<7;nt++){
      bf16x8 b0 = *(const bf16x8*)&TEb[(size_t)(nt*16+l15)*EE + k0 + g*8];
      bf16x8 b1 = *(const bf16x8*)&TEb[(size_t)(nt*16+l15)*EE + k0 + 32 + g*8];
      s[nt] = __builtin_amdgcn_mfma_f32_16x16x32_bf16(af[0], b0, s[nt], 0,0,0);
      s[nt] = __builtin_amdgcn_mfma_f32_16x16x32_bf16(af[1], b1, s[nt], 0,0,0);
    }
  }

  int rowb = m0 + g*4;
#pragma unroll
  for (int nt=0;nt<7;nt++){
    int col = nt*16 + l15;
    if (col < LL){
#pragma unroll
      for (int r=0;r<4;r++)
        scores_out[(size_t)(rowb + r)*LL + col] = s[nt][r];
    }
  }
  if (l15 >= 4){
#pragma unroll
    for (int r=0;r<4;r++) s[6][r] = -1e30f;
  }
  float inv[4];
#pragma unroll
  for (int r=0;r<4;r++){
    float tm = s[0][r];
#pragma unroll
    for (int nt=1;nt<7;nt++) tm = fmaxf(tm, s[nt][r]);
    tm = fmaxf(tm, __shfl_xor(tm, 1, 16));
    tm = fmaxf(tm, __shfl_xor(tm, 2, 16));
    tm = fmaxf(tm, __shfl_xor(tm, 4, 16));
    tm = fmaxf(tm, __shfl_xor(tm, 8, 16));
    float ps = 0.f;
#pragma unroll
    for (int nt=0;nt<7;nt++){
      float p = exp2f((s[nt][r] - tm) * LOG2E);
      s[nt][r] = p; ps += p;
    }
    ps += __shfl_xor(ps, 1, 16);
    ps += __shfl_xor(ps, 2, 16);
    ps += __shfl_xor(ps, 4, 16);
    ps += __shfl_xor(ps, 8, 16);
    inv[r] = 1.f/ps;
  }
#pragma unroll
  for (int nt=0;nt<7;nt++){
    int col = nt*16 + l15;
#pragma unroll
    for (int r=0;r<4;r++)
      att[(size_t)(rowb + r)*128 + col] = f2bf(s[nt][r] * inv[r]);
  }
  {
    int col = 112 + l15;
#pragma unroll
    for (int r=0;r<4;r++) att[(size_t)(rowb + r)*128 + col] = 0;
  }
}

// ---------------------------------------------------------------------------
// fle GEMM (bf16 interior, K=128): HT8 = fp8(X+acc), HU8 = fp8(X+tp).
// ---------------------------------------------------------------------------
__global__ __launch_bounds__(256,1) void gemm_fle_kernel(
    const u16* __restrict__ A, const u16* __restrict__ BTw,
    const float* __restrict__ Xf, const float* __restrict__ tp,
    u8* __restrict__ HT8, u8* __restrict__ HU8, int N, int K)
{
  __shared__ u16 As[128*40];
  __shared__ u16 Bs[128*40];
  int nb = N >> 7;
  int m0 = (blockIdx.x / nb) << 7;
  int n0 = (blockIdx.x % nb) << 7;
  int tid  = threadIdx.x, lane = tid & 63, w = tid >> 6;
  int wm = (w >> 1) << 6, wn = (w & 1) << 6;
  int lr = lane & 15, lk = (lane >> 4) << 3;

  f32x4 acc[4][4] = {};

  for (int k0 = 0; k0 < K; k0 += 32){
    __syncthreads();
#pragma unroll
    for (int i=0;i<2;i++){
      int idx = tid + (i<<8);
      int row = idx >> 2, kq = (idx & 3) << 3;
      *(u16x8*)&As[row*40 + kq] = *(const u16x8*)&A  [(size_t)(m0+row)*K + k0 + kq];
      *(u16x8*)&Bs[row*40 + kq] = *(const u16x8*)&BTw[(size_t)(n0+row)*K + k0 + kq];
    }
    __syncthreads();
    bf16x8 af[4], bfr[4];
#pragma unroll
    for (int i=0;i<4;i++) af [i] = *(const bf16x8*)&As[(wm + i*16 + lr)*40 + lk];
#pragma unroll
    for (int j=0;j<4;j++) bfr[j] = *(const bf16x8*)&Bs[(wn + j*16 + lr)*40 + lk];
#pragma unroll
    for (int i=0;i<4;i++)
#pragma unroll
      for (int j=0;j<4;j++)
        acc[i][j] = __builtin_amdgcn_mfma_f32_16x16x32_bf16(af[i], bfr[j], acc[i][j], 0, 0, 0);
  }

  int rbase = (lane >> 4) << 2;
#pragma unroll
  for (int j=0;j<4;j++){
    int col = n0 + wn + j*16 + lr;
    float tpv = tp[col];
#pragma unroll
    for (int i=0;i<4;i++){
#pragma unroll
      for (int r=0;r<4;r++){
        int row = m0 + wm + i*16 + rbase + r;
        float x = Xf[(size_t)row*EE + col];
        HT8[(size_t)row*EE + col] = f2fp8(x + acc[i][j][r]);
        HU8[(size_t)row*EE + col] = f2fp8(x + tpv);
      }
    }
  }
}

// ---------------------------------------------------------------------------
// gemm8 v4: FP8 projection GEMM (unchanged: frozen R13 k-loop +
// LDS-staged 64B-contiguous store epilogue).
// ---------------------------------------------------------------------------
template<int NB, int FUSED>
__global__ __launch_bounds__(256,2) void gemm8_kernel(
    const u8* __restrict__ A0, const u8* __restrict__ A1,
    const u8* __restrict__ Wb,
    const float* __restrict__ b0, const float* __restrict__ b1,
    const float* __restrict__ b2,
    u16* __restrict__ C0, u16* __restrict__ C1, u16* __restrict__ C2)
{
  __shared__ __align__(16) u8 smem[33792];   // max(As+Bs=32KB, Cs=33792B)
  u8* As = smem;
  u8* Bs = smem + 16384;
  u16* Cs = (u16*)smem;                      // [128][132] bf16
  const int K = EE;   // bytes per row (1B/elt)

  int nwg = gridDim.x;
  int bid = blockIdx.x;
  int cpx = nwg >> 3;
  int swz = (bid & 7) * cpx + (bid >> 3);
  int mb = swz / NB, nb = swz % NB;
  int m0 = mb << 7;
  int n0 = (FUSED ? (nb % 6) : nb) << 7;

  int which = FUSED ? (nb / 6) : 0;
  const u8* Ap; const u8* Wp; const float* bp; u16* Cp;
  if (!FUSED){ Ap = A0; Wp = Wb; bp = b0; Cp = C0; }
  else {
    if (which == 0){ Ap = A0; Wp = Wb;                      bp = b0; Cp = C0; }
    else if (which == 1){ Ap = A1; Wp = Wb + (size_t)EE*EE; bp = b1; Cp = C1; }
    else { Ap = A1; Wp = Wb + 2*(size_t)EE*EE;              bp = b2; Cp = C2; }
  }

  int tid = threadIdx.x, lane = tid & 63, w = tid >> 6;
  int wm = (w >> 1) << 6, wn = (w & 1) << 6;
  int lr = lane & 15, g = lane >> 4;
  int lrow = lane >> 3;
  int lchunk = (lane & 7) ^ lrow;          // source pre-swizzle (rule #21)

  f32x4 acc[4][4] = {};

  for (int k0 = 0; k0 < K; k0 += 128){
    __syncthreads();
#pragma unroll
    for (int t=0;t<4;t++){
      int r0 = w*32 + t*8;
      gload16(&Ap[(size_t)(m0 + r0 + lrow)*K + k0 + (lchunk<<4)], &As[r0*128]);
      gload16(&Wp[(size_t)(n0 + r0 + lrow)*K + k0 + (lchunk<<4)], &Bs[r0*128]);
    }
    __syncthreads();
#pragma unroll
    for (int t=0;t<2;t++){
      int cs = ((t<<2) + g) ^ (lr & 7);    // 16B chunk; zero-conflict pattern
      longx2 af[4], bfr[4];
#pragma unroll
      for (int i=0;i<4;i++) af [i] = *(const longx2*)&As[(wm + i*16 + lr)*128 + (cs<<4)];
#pragma unroll
      for (int j=0;j<4;j++) bfr[j] = *(const longx2*)&Bs[(wn + j*16 + lr)*128 + (cs<<4)];
#pragma unroll
      for (int i=0;i<4;i++)
#pragma unroll
        for (int j=0;j<4;j++){
          acc[i][j] = __builtin_amdgcn_mfma_f32_16x16x32_fp8_fp8(af[i][0], bfr[j][0], acc[i][j], 0, 0, 0);
          acc[i][j] = __builtin_amdgcn_mfma_f32_16x16x32_fp8_fp8(af[i][1], bfr[j][1], acc[i][j], 0, 0, 0);
        }
    }
  }

  // ---- epilogue via LDS: Cs[row][col], stride 132 ----
  int rbase = (lane >> 4) << 2;
  float scq = (FUSED && which==0) ? QSCALE : 1.0f;
  __syncthreads();                         // all As/Bs reads complete
#pragma unroll
  for (int j=0;j<4;j++){
    int col = wn + j*16 + lr;
    float bv = bp[n0 + col];
#pragma unroll
    for (int i=0;i<4;i++)
#pragma unroll
      for (int r=0;r<4;r++)
        Cs[(wm + i*16 + rbase + r)*132 + col] = f2bf((acc[i][j][r] + bv) * scq);
  }
  __syncthreads();

  if (FUSED && which == 2){
    // V transposed: VT[(bb*HH+hh)*DD+d][t]. 4 lanes cover 64B contiguous t.
    int bb = m0 >> 9, t0 = m0 & 511;
    int colb = tid >> 2;                   // 0..63
    int tq = (tid & 3) << 3;               // 0,8,16,24
#pragma unroll
    for (int c2=0;c2<2;c2++){
      int col = colb + (c2<<6);            // 0..127
      int hh = (n0 + col) >> 6, d = (n0 + col) & 63;
      u16* dst = &Cp[((size_t)(bb*HH + hh)*DD + d)*TT + t0];
#pragma unroll
      for (int s=0;s<4;s++){
        int tt = tq + (s<<5);
        u16x8 v;
#pragma unroll
        for (int e=0;e<8;e++) v[e] = Cs[(tt+e)*132 + col];
        *(u16x8*)&dst[tt] = v;
      }
    }
  } else {
    // Q/K/O row-major: 4 lanes x 16B = 64B contiguous per quad.
#pragma unroll
    for (int p=0;p<2;p++){
      int row = (tid >> 2) + (p<<6);       // 0..127
      int c0 = (tid & 3) << 3;             // 0,8,16,24
      size_t gbase = (size_t)(m0 + row)*EE + n0;
      const u16* src = &Cs[row*132];
#pragma unroll
      for (int s=0;s<4;s++){
        int c = c0 + (s<<5);
        u16x4 lo = *(const u16x4*)&src[c];
        u16x4 hi = *(const u16x4*)&src[c+4];
        u16x8 v;
#pragma unroll
        for (int e=0;e<4;e++){ v[e] = lo[e]; v[e+4] = hi[e]; }
        *(u16x8*)&Cp[gbase + c] = v;
      }
    }
  }
}

// ---------------------------------------------------------------------------
// K4: MFMA flash attention v6 — exact R16 structure (dbuf STAGE, mb-before-
// STAGE, launch_bounds(256,3) => VGPR 84, no spill) with ONLY the verified
// PSTR 72->76 bank fix (pa b128 re-reads were 8-way at stride 72; 76 gives
// (6*l15+4g)%32 starts = <=2-way; R17 measured conflicts 737K->344K).
// LDS 52.2KB -> still 3 blocks/CU.
// ---------------------------------------------------------------------------
__global__ __launch_bounds__(256,3) void attn_mfma_kernel(
    const u16* __restrict__ Q, const u16* __restrict__ K,
    const u16* __restrict__ VT, const float* __restrict__ MBg,
    u8* __restrict__ CTX8)
{
  __shared__ u16 Ks [2][64*64];
  __shared__ u16 VTs[2][64*64];
  __shared__ u16 Pl [4][32*PSTR];

  int bx = blockIdx.x;
  int bh = bx % (BB*HH), q0 = (bx / (BB*HH)) << 7;
  int b = bh / HH, h = bh % HH;
  int tid = threadIdx.x, lane = tid & 63, w = tid >> 6;
  int l15 = lane & 15, g = lane >> 4;
  int wq0 = q0 + w*32;
  size_t rowbase = (size_t)b*TT;
  u16* pw = &Pl[w][0];
  const u16* Kbh = K  + rowbase*EE + h*DD;
  const u16* Vbh = VT + (size_t)bh*DD*TT;
  int lrow = lane >> 3, lchunk = (lane & 7) ^ (lane >> 3);

  bf16x8 qf[2][2];
#pragma unroll
  for (int i=0;i<2;i++)
#pragma unroll
    for (int kk=0;kk<2;kk++)
      qf[i][kk] = *(const bf16x8*)&Q[(rowbase + wq0 + i*16 + l15)*EE + h*DD + kk*32 + g*8];

  f32x4 ctxf[2][4] = {};
  float lrun[2][4] = {};

#define STAGE(buf, k0)                                                          \
  { _Pragma("unroll")                                                           \
    for (int it=0; it<2; ++it){                                                 \
      int r0 = w*16 + it*8;                                                     \
      gload16(&Kbh[(size_t)((k0) + r0 + lrow)*EE + (lchunk<<3)], &Ks [buf][r0*64]); \
      gload16(&Vbh[(size_t)(r0 + lrow)*TT + (k0) + (lchunk<<3)], &VTs[buf][r0*64]); } }

  STAGE(0, 0);

  for (int kt=0; kt<8; ++kt){
    int k0 = kt << 6;
    int buf = kt & 1;
    __syncthreads();

    // mb loads FIRST (older than stage loads -> compiler waits vmcnt(4))
    float mb[4];
#pragma unroll
    for (int kb=0;kb<4;kb++) mb[kb] = MBg[rowbase + k0 + kb*16 + l15];

    if (kt < 7) STAGE(buf^1, k0+64);

    f32x4 s[2][4] = {};
#pragma unroll
    for (int kk=0;kk<2;kk++){
      int cs = ((kk<<2) + g) ^ (l15 & 7);
      bf16x8 kf[4];
#pragma unroll
      for (int kb=0;kb<4;kb++)
        kf[kb] = *(const bf16x8*)&Ks[buf][(kb*16 + l15)*64 + (cs<<3)];
#pragma unroll
      for (int i=0;i<2;i++)
#pragma unroll
        for (int kb=0;kb<4;kb++)
          s[i][kb] = __builtin_amdgcn_mfma_f32_16x16x32_bf16(qf[i][kk], kf[kb], s[i][kb], 0,0,0);
    }

    if ((k0 < wq0 + 32) && (k0 + 64 > wq0)){
#pragma unroll
      for (int i=0;i<2;i++){
        int qr = wq0 + i*16 + g*4;
#pragma unroll
        for (int kb=0;kb<4;kb++){
          int kpos = k0 + kb*16 + l15;
#pragma unroll
          for (int r=0;r<4;r++)
            if (kpos == qr + r) s[i][kb][r] -= 1e9f*LOG2E;
        }
      }
    }

#pragma unroll
    for (int i=0;i<2;i++)
#pragma unroll
      for (int kb=0;kb<4;kb++)
#pragma unroll
        for (int r=0;r<4;r++){
          float p = exp2f(s[i][kb][r] + mb[kb]);
          lrun[i][r] += p;
          pw[(i*16 + g*4 + r)*PSTR + kb*16 + l15] = f2bf(p);
        }

    bf16x8 pa[2][2];
#pragma unroll
    for (int i=0;i<2;i++)
#pragma unroll
      for (int kk=0;kk<2;kk++)
        pa[i][kk] = *(const bf16x8*)&pw[(i*16 + l15)*PSTR + kk*32 + g*8];

#pragma unroll
    for (int kk=0;kk<2;kk++){
      int cs = ((kk<<2) + g) ^ (l15 & 7);
      bf16x8 vf[4];
#pragma unroll
      for (int dj=0;dj<4;dj++)
        vf[dj] = *(const bf16x8*)&VTs[buf][(dj*16 + l15)*64 + (cs<<3)];
#pragma unroll
      for (int i=0;i<2;i++)
#pragma unroll
        for (int dj=0;dj<4;dj++)
          ctxf[i][dj] = __builtin_amdgcn_mfma_f32_16x16x32_bf16(pa[i][kk], vf[dj], ctxf[i][dj], 0,0,0);
    }
  }
#undef STAGE

  float inv[2][4];
#pragma unroll
  for (int i=0;i<2;i++)
#pragma unroll
    for (int r=0;r<4;r++){
      float l = lrun[i][r];
      l += __shfl_xor(l, 1, 16);
      l += __shfl_xor(l, 2, 16);
      l += __shfl_xor(l, 4, 16);
      l += __shfl_xor(l, 8, 16);
      inv[i][r] = 1.0f / l;
    }
#pragma unroll
  for (int i=0;i<2;i++)
#pragma unroll
    for (int dj=0;dj<4;dj++)
#pragma unroll
      for (int r=0;r<4;r++)
        pw[(i*16 + g*4 + r)*64 + dj*16 + l15] = f2bf(ctxf[i][dj][r] * inv[i][r]);
#pragma unroll
  for (int t=0;t<4;t++){
    int row = lane >> 1, c = ((lane & 1)<<5) + t*8;
    const u16* pv = &pw[row*64 + c];
    u16x4 o8;
#pragma unroll
    for (int e=0;e<4;e++) o8[e] = pk_fp8(bf2f(pv[2*e]), bf2f(pv[2*e+1]));
    *(u16x4*)&CTX8[(rowbase + wq0 + row)*EE + h*DD + c] = o8;
  }
}

// ---------------------------------------------------------------------------
// K5: LayerNorm(AO + HU)*g + b + HT -> out (f32). HU/HT read as fp8.
// ---------------------------------------------------------------------------
__global__ __launch_bounds__(192,1) void ln_out_kernel(
    const u16* __restrict__ AO, const u8* __restrict__ HU8,
    const u8* __restrict__ HT8, const float* __restrict__ g,
    const float* __restrict__ bta, float* __restrict__ out)
{
  __shared__ float red[3];
  int r = blockIdx.x, tid = threadIdx.x;
  size_t base = (size_t)r*EE;
  int e0 = tid*4;
  u16x4 ao = *(const u16x4*)&AO[base+e0];
  int hu4 = *(const int*)&HU8[base+e0];
  int ht4 = *(const int*)&HT8[base+e0];
  f32x2 hulo = __builtin_amdgcn_cvt_pk_f32_fp8(hu4, false);
  f32x2 huhi = __builtin_amdgcn_cvt_pk_f32_fp8(hu4, true);
  f32x2 htlo = __builtin_amdgcn_cvt_pk_f32_fp8(ht4, false);
  f32x2 hthi = __builtin_amdgcn_cvt_pk_f32_fp8(ht4, true);
  float huv[4] = {hulo[0], hulo[1], huhi[0], huhi[1]};
  float htv[4] = {htlo[0], htlo[1], hthi[0], hthi[1]};
  float x[4];
#pragma unroll
  for (int j=0;j<4;j++) x[j] = bf2f(ao[j]) + huv[j];

  float s = x[0]+x[1]+x[2]+x[3];
#pragma unroll
  for (int o=32;o;o>>=1) s += __shfl_xor(s, o, 64);
  int w = tid>>6;
  if ((tid&63)==0) red[w] = s;
  __syncthreads();
  float mu = (red[0]+red[1]+red[2]) * (1.0f/EE);
  __syncthreads();
  float d2 = 0.f;
#pragma unroll
  for (int j=0;j<4;j++){ float d = x[j]-mu; d2 += d*d; }
#pragma unroll
  for (int o=32;o;o>>=1) d2 += __shfl_xor(d2, o, 64);
  if ((tid&63)==0) red[w] = d2;
  __syncthreads();
  float var = (red[0]+red[1]+red[2]) * (1.0f/EE);
  float rs = rsqrtf(var + 1e-12f);
  float4 gg = *(const float4*)&g[e0];
  float4 bb = *(const float4*)&bta[e0];
  float4 o4;
  o4.x = (x[0]-mu)*rs*gg.x + bb.x + htv[0];
  o4.y = (x[1]-mu)*rs*gg.y + bb.y + htv[1];
  o4.z = (x[2]-mu)*rs*gg.z + bb.z + htv[2];
  o4.w = (x[3]-mu)*rs*gg.w + bb.w + htv[3];
  *(float4*)&out[base+e0] = o4;
}

// ---------------------------------------------------------------------------
extern "C" void kernel_launch(void* const* d_in, const int* in_sizes, int n_in,
                              void* d_out, int out_size, void* d_ws, size_t ws_size,
                              hipStream_t stream)
{
  (void)in_sizes; (void)n_in; (void)out_size; (void)ws_size;
  const float* X    = (const float*)d_in[0];
  const float* mask = (const float*)d_in[1];
  const float* TE   = (const float*)d_in[2];
  const float* tp   = (const float*)d_in[3];
  const float* Wq   = (const float*)d_in[4];
  const float* bq   = (const float*)d_in[5];
  const float* Wk   = (const float*)d_in[6];
  const float* bk   = (const float*)d_in[7];
  const float* Wv   = (const float*)d_in[8];
  const float* bv   = (const float*)d_in[9];
  const float* Wo   = (const float*)d_in[10];
  const float* bo   = (const float*)d_in[11];
  const float* ln_g = (const float*)d_in[12];
  const float* ln_b = (const float*)d_in[13];

  float* out    = (float*)d_out;
  float* scores = out + BTE;

  char* p = (char*)d_ws;
  u8*  HT8  = (u8*)p;  p += BTE;                 // fp8 [8192][768]
  u8*  HU8  = (u8*)p;  p += BTE;
  u8*  CTX8 = (u8*)p;  p += BTE;
  u8*  WT8  = (u8*)p;  p += (size_t)4*EE*EE;     // fp8 4x[768][768] transposed
  u16* Qb   = (u16*)p; p += BTE*2;               // bf16
  u16* Kb   = (u16*)p; p += BTE*2;
  u16* VTb  = (u16*)p; p += BTE*2;               // bf16 [bh*64+d][512]
  u16* AOb  = (u16*)p; p += BTE*2;
  u16* ATT  = (u16*)p; p += (size_t)BT*128*2;    // bf16 [8192][128]
  u16* TEb  = (u16*)p; p += (size_t)128*EE*2;
  u16* TEt  = (u16*)p; p += (size_t)EE*128*2;
  float* MBg = (float*)p;

  prep_all_kernel<<<dim3(992), dim3(256), 0, stream>>>(
      Wq, Wk, Wv, Wo, WT8, TE, TEb, TEt, mask, MBg);

  label_scores_kernel<<<dim3(BT/16), dim3(64), 0, stream>>>(X, TEb, scores, ATT);

  // fle GEMM + fused fp8 HT/HU epilogue: M=8192, N=768, K=128
  gemm_fle_kernel<<<dim3((BT/128)*(EE/128)), dim3(256), 0, stream>>>(
      ATT, TEt, X, tp, HT8, HU8, EE, 128);

  // fused QKV projections (fp8 inputs, bf16 outputs): 64 m x 18 n
  gemm8_kernel<18,1><<<dim3(64*18), dim3(256), 0, stream>>>(
      HU8, HT8, WT8, bq, bk, bv, Qb, Kb, VTb);

  attn_mfma_kernel<<<dim3(BB*HH*4), dim3(256), 0, stream>>>(Qb, Kb, VTb, MBg, CTX8);

  // O projection (fp8 inputs): 64 x 6
  gemm8_kernel<6,0><<<dim3(64*6), dim3(256), 0, stream>>>(
      CTX8, nullptr, WT8 + 3*(size_t)EE*EE, bo, nullptr, nullptr, AOb, nullptr, nullptr);

  ln_out_kernel<<<dim3(BT), dim3(192), 0, stream>>>(AOb, HU8, HT8, ln_g, ln_b, out);
}

// Round 19
// 114.621 us; speedup vs baseline: 1.2352x; 1.0616x over previous
//
#include <hip/hip_runtime.h>

typedef unsigned char u8;
typedef unsigned short u16;
typedef u16 u16x4 __attribute__((ext_vector_type(4)));
typedef u16 u16x8 __attribute__((ext_vector_type(8)));
typedef __bf16 bf16x8 __attribute__((ext_vector_type(8)));
typedef float f32x2 __attribute__((ext_vector_type(2)));
typedef float f32x4 __attribute__((ext_vector_type(4)));
typedef long longx2 __attribute__((ext_vector_type(2)));

#define BB 16
#define TT 512
#define EE 768
#define HH 12
#define DD 64
#define LL 100
#define BT (BB*TT)             /* 8192 */
#define BTE ((size_t)BT*EE)    /* 6291456 */
#define LOG2E 1.44269504f
#define QSCALE (0.125f*LOG2E)  /* 1/sqrt(D)*log2e, folded into Q projection */
#define FIXMAX 44.0f           /* fixed softmax shift (log2 domain) */
#define PSTR 72                /* Pl row stride: 144B = 16B-ALIGNED (b128 pa reads).
                                  76 (2-way writes) regressed: rows lose 16B alignment
                                  -> split ds_reads cost more than conflicts saved. */

__device__ __forceinline__ float bf2f(u16 u){
  union { float f; unsigned int i; } v; v.i = ((unsigned int)u) << 16; return v.f;
}
__device__ __forceinline__ u16 f2bf(float f){
  __bf16 h = (__bf16)f;
  union { __bf16 h; u16 u; } v; v.h = h; return v.u;
}
// fp8 e4m3 (OCP on gfx950) pack/unpack via HW cvt
__device__ __forceinline__ u16 pk_fp8(float a, float b){
  return (u16)(__builtin_amdgcn_cvt_pk_fp8_f32(a, b, 0, false) & 0xffff);
}
__device__ __forceinline__ u8 f2fp8(float a){
  return (u8)(__builtin_amdgcn_cvt_pk_fp8_f32(a, 0.f, 0, false) & 0xff);
}

// async 16B global->LDS DMA. LDS dest = wave-uniform base + lane*16.
__device__ __forceinline__ void gload16(const void* g, void* l){
  __builtin_amdgcn_global_load_lds(
      (const __attribute__((address_space(1))) void*)g,
      (__attribute__((address_space(3))) void*)l, 16, 0, 0);
}

// ---------------------------------------------------------------------------
// Merged prep: blocks 0-575 transpose+cast W[4] into FP8 [N][K];
// blocks 576-959 build TEb[128][768] / TEt[768][128] bf16; 960-991 mask bias.
// ---------------------------------------------------------------------------
__global__ __launch_bounds__(256,1) void prep_all_kernel(
    const float* __restrict__ Wq, const float* __restrict__ Wk,
    const float* __restrict__ Wv, const float* __restrict__ Wo,
    u8* __restrict__ WT8,
    const float* __restrict__ TE, u16* __restrict__ TEb, u16* __restrict__ TEt,
    const float* __restrict__ mask, float* __restrict__ MBg)
{
  __shared__ float tile[64][65];
  int bx = blockIdx.x;
  int tid = threadIdx.x;
  if (bx < 576){
    int m  = bx / 144, t = bx % 144;
    int tr = t / 12,  tc = t % 12;
    const float* W = (m==0)?Wq : (m==1)?Wk : (m==2)?Wv : Wo;
    u8* dst = WT8 + (size_t)m * EE * EE;
#pragma unroll
    for (int i=0;i<16;i++){
      int idx = tid + 256*i; int r = idx>>6, c = idx&63;
      tile[r][c] = W[(size_t)(tr*64+r)*EE + tc*64 + c];
    }
    __syncthreads();
    // dst[n][k] = W[k][n] in fp8, packed pairs along k
#pragma unroll
    for (int i=0;i<8;i++){
      int idx = tid + 256*i;          // 2048 = 64 r x 32 col-pairs
      int r = idx >> 5, cp = idx & 31;
      u16 pk = pk_fp8(tile[cp*2][r], tile[cp*2+1][r]);
      *(u16*)&dst[(size_t)(tc*64+r)*EE + tr*64 + cp*2] = pk;
    }
  } else if (bx < 960){
    int e = (bx - 576)*2 + (tid >> 7);
    int c = tid & 127;
    u16 v = 0;
    if (c < LL) v = f2bf(TE[(size_t)c*EE + e]);
    TEt[(size_t)e*128 + c] = v;
    if (e < 128){
#pragma unroll
      for (int k=c; k<EE; k+=128)
        TEb[(size_t)e*EE + k] = (e < LL) ? f2bf(TE[(size_t)e*EE + k]) : (u16)0;
    }
  } else {
    int i = (bx - 960)*256 + tid;
    MBg[i] = (1.0f - mask[i]) * (-1e9f * LOG2E) - FIXMAX;
  }
}

// ---------------------------------------------------------------------------
// K1 v2: label scores + softmax, LDS-free (unchanged).
// ---------------------------------------------------------------------------
__global__ __launch_bounds__(64) void label_scores_kernel(
    const float* __restrict__ X, const u16* __restrict__ TEb,
    float* __restrict__ scores_out, u16* __restrict__ att)
{
  int m0 = blockIdx.x * 16;
  int lane = threadIdx.x;
  int l15 = lane & 15, g = lane >> 4;

  const float* xrow = X + (size_t)(m0 + l15)*EE;
  f32x4 s[7] = {};
  for (int k0=0; k0<EE; k0+=64){
    bf16x8 af[2];
#pragma unroll
    for (int kk=0;kk<2;kk++){
      const float* src = xrow + k0 + kk*32 + g*8;
      float4 a = *(const float4*)src, b = *(const float4*)(src+4);
      bf16x8 o;
      o[0]=(__bf16)a.x; o[1]=(__bf16)a.y; o[2]=(__bf16)a.z; o[3]=(__bf16)a.w;
      o[4]=(__bf16)b.x; o[5]=(__bf16)b.y; o[6]=(__bf16)b.z; o[7]=(__bf16)b.w;
      af[kk] = o;
    }
#pragma unroll
    for (int nt=0;nt<7;nt++){
      bf16x8 b0 = *(const bf16x8*)&TEb[(size_t)(nt*16+l15)*EE + k0 + g*8];
      bf16x8 b1 = *(const bf16x8*)&TEb[(size_t)(nt*16+l15)*EE + k0 + 32 + g*8];
      s[nt] = __builtin_amdgcn_mfma_f32_16x16x32_bf16(af[0], b0, s[nt], 0,0,0);
      s[nt] = __builtin_amdgcn_mfma_f32_16x16x32_bf16(af[1], b1, s[nt], 0,0,0);
    }
  }

  int rowb = m0 + g*4;
#pragma unroll
  for (int nt=0;nt<7;nt++){
    int col = nt*16 + l15;
    if (col < LL){
#pragma unroll
      for (int r=0;r<4;r++)
        scores_out[(size_t)(rowb + r)*LL + col] = s[nt][r];
    }
  }
  if (l15 >= 4){
#pragma unroll
    for (int r=0;r<4;r++) s[6][r] = -1e30f;
  }
  float inv[4];
#pragma unroll
  for (int r=0;r<4;r++){
    float tm = s[0][r];
#pragma unroll
    for (int nt=1;nt<7;nt++) tm = fmaxf(tm, s[nt][r]);
    tm = fmaxf(tm, __shfl_xor(tm, 1, 16));
    tm = fmaxf(tm, __shfl_xor(tm, 2, 16));
    tm = fmaxf(tm, __shfl_xor(tm, 4, 16));
    tm = fmaxf(tm, __shfl_xor(tm, 8, 16));
    float ps = 0.f;
#pragma unroll
    for (int nt=0;nt<7;nt++){
      float p = exp2f((s[nt][r] - tm) * LOG2E);
      s[nt][r] = p; ps += p;
    }
    ps += __shfl_xor(ps, 1, 16);
    ps += __shfl_xor(ps, 2, 16);
    ps += __shfl_xor(ps, 4, 16);
    ps += __shfl_xor(ps, 8, 16);
    inv[r] = 1.f/ps;
  }
#pragma unroll
  for (int nt=0;nt<7;nt++){
    int col = nt*16 + l15;
#pragma unroll
    for (int r=0;r<4;r++)
      att[(size_t)(rowb + r)*128 + col] = f2bf(s[nt][r] * inv[r]);
  }
  {
    int col = 112 + l15;
#pragma unroll
    for (int r=0;r<4;r++) att[(size_t)(rowb + r)*128 + col] = 0;
  }
}

// ---------------------------------------------------------------------------
// fle GEMM (bf16 interior, K=128): HT8 = fp8(X+acc), HU8 = fp8(X+tp).
// ---------------------------------------------------------------------------
__global__ __launch_bounds__(256,1) void gemm_fle_kernel(
    const u16* __restrict__ A, const u16* __restrict__ BTw,
    const float* __restrict__ Xf, const float* __restrict__ tp,
    u8* __restrict__ HT8, u8* __restrict__ HU8, int N, int K)
{
  __shared__ u16 As[128*40];
  __shared__ u16 Bs[128*40];
  int nb = N >> 7;
  int m0 = (blockIdx.x / nb) << 7;
  int n0 = (blockIdx.x % nb) << 7;
  int tid  = threadIdx.x, lane = tid & 63, w = tid >> 6;
  int wm = (w >> 1) << 6, wn = (w & 1) << 6;
  int lr = lane & 15, lk = (lane >> 4) << 3;

  f32x4 acc[4][4] = {};

  for (int k0 = 0; k0 < K; k0 += 32){
    __syncthreads();
#pragma unroll
    for (int i=0;i<2;i++){
      int idx = tid + (i<<8);
      int row = idx >> 2, kq = (idx & 3) << 3;
      *(u16x8*)&As[row*40 + kq] = *(const u16x8*)&A  [(size_t)(m0+row)*K + k0 + kq];
      *(u16x8*)&Bs[row*40 + kq] = *(const u16x8*)&BTw[(size_t)(n0+row)*K + k0 + kq];
    }
    __syncthreads();
    bf16x8 af[4], bfr[4];
#pragma unroll
    for (int i=0;i<4;i++) af [i] = *(const bf16x8*)&As[(wm + i*16 + lr)*40 + lk];
#pragma unroll
    for (int j=0;j<4;j++) bfr[j] = *(const bf16x8*)&Bs[(wn + j*16 + lr)*40 + lk];
#pragma unroll
    for (int i=0;i<4;i++)
#pragma unroll
      for (int j=0;j<4;j++)
        acc[i][j] = __builtin_amdgcn_mfma_f32_16x16x32_bf16(af[i], bfr[j], acc[i][j], 0, 0, 0);
  }

  int rbase = (lane >> 4) << 2;
#pragma unroll
  for (int j=0;j<4;j++){
    int col = n0 + wn + j*16 + lr;
    float tpv = tp[col];
#pragma unroll
    for (int i=0;i<4;i++){
#pragma unroll
      for (int r=0;r<4;r++){
        int row = m0 + wm + i*16 + rbase + r;
        float x = Xf[(size_t)row*EE + col];
        HT8[(size_t)row*EE + col] = f2fp8(x + acc[i][j][r]);
        HU8[(size_t)row*EE + col] = f2fp8(x + tpv);
      }
    }
  }
}

// ---------------------------------------------------------------------------
// gemm8 v4: FP8 projection GEMM (unchanged: frozen R13 k-loop +
// LDS-staged 64B-contiguous store epilogue).
// ---------------------------------------------------------------------------
template<int NB, int FUSED>
__global__ __launch_bounds__(256,2) void gemm8_kernel(
    const u8* __restrict__ A0, const u8* __restrict__ A1,
    const u8* __restrict__ Wb,
    const float* __restrict__ b0, const float* __restrict__ b1,
    const float* __restrict__ b2,
    u16* __restrict__ C0, u16* __restrict__ C1, u16* __restrict__ C2)
{
  __shared__ __align__(16) u8 smem[33792];   // max(As+Bs=32KB, Cs=33792B)
  u8* As = smem;
  u8* Bs = smem + 16384;
  u16* Cs = (u16*)smem;                      // [128][132] bf16
  const int K = EE;   // bytes per row (1B/elt)

  int nwg = gridDim.x;
  int bid = blockIdx.x;
  int cpx = nwg >> 3;
  int swz = (bid & 7) * cpx + (bid >> 3);
  int mb = swz / NB, nb = swz % NB;
  int m0 = mb << 7;
  int n0 = (FUSED ? (nb % 6) : nb) << 7;

  int which = FUSED ? (nb / 6) : 0;
  const u8* Ap; const u8* Wp; const float* bp; u16* Cp;
  if (!FUSED){ Ap = A0; Wp = Wb; bp = b0; Cp = C0; }
  else {
    if (which == 0){ Ap = A0; Wp = Wb;                      bp = b0; Cp = C0; }
    else if (which == 1){ Ap = A1; Wp = Wb + (size_t)EE*EE; bp = b1; Cp = C1; }
    else { Ap = A1; Wp = Wb + 2*(size_t)EE*EE;              bp = b2; Cp = C2; }
  }

  int tid = threadIdx.x, lane = tid & 63, w = tid >> 6;
  int wm = (w >> 1) << 6, wn = (w & 1) << 6;
  int lr = lane & 15, g = lane >> 4;
  int lrow = lane >> 3;
  int lchunk = (lane & 7) ^ lrow;          // source pre-swizzle (rule #21)

  f32x4 acc[4][4] = {};

  for (int k0 = 0; k0 < K; k0 += 128){
    __syncthreads();
#pragma unroll
    for (int t=0;t<4;t++){
      int r0 = w*32 + t*8;
      gload16(&Ap[(size_t)(m0 + r0 + lrow)*K + k0 + (lchunk<<4)], &As[r0*128]);
      gload16(&Wp[(size_t)(n0 + r0 + lrow)*K + k0 + (lchunk<<4)], &Bs[r0*128]);
    }
    __syncthreads();
#pragma unroll
    for (int t=0;t<2;t++){
      int cs = ((t<<2) + g) ^ (lr & 7);    // 16B chunk; zero-conflict pattern
      longx2 af[4], bfr[4];
#pragma unroll
      for (int i=0;i<4;i++) af [i] = *(const longx2*)&As[(wm + i*16 + lr)*128 + (cs<<4)];
#pragma unroll
      for (int j=0;j<4;j++) bfr[j] = *(const longx2*)&Bs[(wn + j*16 + lr)*128 + (cs<<4)];
#pragma unroll
      for (int i=0;i<4;i++)
#pragma unroll
        for (int j=0;j<4;j++){
          acc[i][j] = __builtin_amdgcn_mfma_f32_16x16x32_fp8_fp8(af[i][0], bfr[j][0], acc[i][j], 0, 0, 0);
          acc[i][j] = __builtin_amdgcn_mfma_f32_16x16x32_fp8_fp8(af[i][1], bfr[j][1], acc[i][j], 0, 0, 0);
        }
    }
  }

  // ---- epilogue via LDS: Cs[row][col], stride 132 ----
  int rbase = (lane >> 4) << 2;
  float scq = (FUSED && which==0) ? QSCALE : 1.0f;
  __syncthreads();                         // all As/Bs reads complete
#pragma unroll
  for (int j=0;j<4;j++){
    int col = wn + j*16 + lr;
    float bv = bp[n0 + col];
#pragma unroll
    for (int i=0;i<4;i++)
#pragma unroll
      for (int r=0;r<4;r++)
        Cs[(wm + i*16 + rbase + r)*132 + col] = f2bf((acc[i][j][r] + bv) * scq);
  }
  __syncthreads();

  if (FUSED && which == 2){
    // V transposed: VT[(bb*HH+hh)*DD+d][t]. 4 lanes cover 64B contiguous t.
    int bb = m0 >> 9, t0 = m0 & 511;
    int colb = tid >> 2;                   // 0..63
    int tq = (tid & 3) << 3;               // 0,8,16,24
#pragma unroll
    for (int c2=0;c2<2;c2++){
      int col = colb + (c2<<6);            // 0..127
      int hh = (n0 + col) >> 6, d = (n0 + col) & 63;
      u16* dst = &Cp[((size_t)(bb*HH + hh)*DD + d)*TT + t0];
#pragma unroll
      for (int s=0;s<4;s++){
        int tt = tq + (s<<5);
        u16x8 v;
#pragma unroll
        for (int e=0;e<8;e++) v[e] = Cs[(tt+e)*132 + col];
        *(u16x8*)&dst[tt] = v;
      }
    }
  } else {
    // Q/K/O row-major: 4 lanes x 16B = 64B contiguous per quad.
#pragma unroll
    for (int p=0;p<2;p++){
      int row = (tid >> 2) + (p<<6);       // 0..127
      int c0 = (tid & 3) << 3;             // 0,8,16,24
      size_t gbase = (size_t)(m0 + row)*EE + n0;
      const u16* src = &Cs[row*132];
#pragma unroll
      for (int s=0;s<4;s++){
        int c = c0 + (s<<5);
        u16x4 lo = *(const u16x4*)&src[c];
        u16x4 hi = *(const u16x4*)&src[c+4];
        u16x8 v;
#pragma unroll
        for (int e=0;e<4;e++){ v[e] = lo[e]; v[e+4] = hi[e]; }
        *(u16x8*)&Cp[gbase + c] = v;
      }
    }
  }
}

// ---------------------------------------------------------------------------
// K4: MFMA flash attention — exact R16 config (session best, 40us):
// dbuf STAGE, mb-before-STAGE (vmcnt(4) wait), launch_bounds(256,3),
// PSTR=72 (16B-aligned Pl rows -> single ds_read_b128 pa loads).
// ---------------------------------------------------------------------------
__global__ __launch_bounds__(256,3) void attn_mfma_kernel(
    const u16* __restrict__ Q, const u16* __restrict__ K,
    const u16* __restrict__ VT, const float* __restrict__ MBg,
    u8* __restrict__ CTX8)
{
  __shared__ u16 Ks [2][64*64];
  __shared__ u16 VTs[2][64*64];
  __shared__ u16 Pl [4][32*PSTR];

  int bx = blockIdx.x;
  int bh = bx % (BB*HH), q0 = (bx / (BB*HH)) << 7;
  int b = bh / HH, h = bh % HH;
  int tid = threadIdx.x, lane = tid & 63, w = tid >> 6;
  int l15 = lane & 15, g = lane >> 4;
  int wq0 = q0 + w*32;
  size_t rowbase = (size_t)b*TT;
  u16* pw = &Pl[w][0];
  const u16* Kbh = K  + rowbase*EE + h*DD;
  const u16* Vbh = VT + (size_t)bh*DD*TT;
  int lrow = lane >> 3, lchunk = (lane & 7) ^ (lane >> 3);

  bf16x8 qf[2][2];
#pragma unroll
  for (int i=0;i<2;i++)
#pragma unroll
    for (int kk=0;kk<2;kk++)
      qf[i][kk] = *(const bf16x8*)&Q[(rowbase + wq0 + i*16 + l15)*EE + h*DD + kk*32 + g*8];

  f32x4 ctxf[2][4] = {};
  float lrun[2][4] = {};

#define STAGE(buf, k0)                                                          \
  { _Pragma("unroll")                                                           \
    for (int it=0; it<2; ++it){                                                 \
      int r0 = w*16 + it*8;                                                     \
      gload16(&Kbh[(size_t)((k0) + r0 + lrow)*EE + (lchunk<<3)], &Ks [buf][r0*64]); \
      gload16(&Vbh[(size_t)(r0 + lrow)*TT + (k0) + (lchunk<<3)], &VTs[buf][r0*64]); } }

  STAGE(0, 0);

  for (int kt=0; kt<8; ++kt){
    int k0 = kt << 6;
    int buf = kt & 1;
    __syncthreads();

    // mb loads FIRST (older than stage loads -> compiler waits vmcnt(4))
    float mb[4];
#pragma unroll
    for (int kb=0;kb<4;kb++) mb[kb] = MBg[rowbase + k0 + kb*16 + l15];

    if (kt < 7) STAGE(buf^1, k0+64);

    f32x4 s[2][4] = {};
#pragma unroll
    for (int kk=0;kk<2;kk++){
      int cs = ((kk<<2) + g) ^ (l15 & 7);
      bf16x8 kf[4];
#pragma unroll
      for (int kb=0;kb<4;kb++)
        kf[kb] = *(const bf16x8*)&Ks[buf][(kb*16 + l15)*64 + (cs<<3)];
#pragma unroll
      for (int i=0;i<2;i++)
#pragma unroll
        for (int kb=0;kb<4;kb++)
          s[i][kb] = __builtin_amdgcn_mfma_f32_16x16x32_bf16(qf[i][kk], kf[kb], s[i][kb], 0,0,0);
    }

    if ((k0 < wq0 + 32) && (k0 + 64 > wq0)){
#pragma unroll
      for (int i=0;i<2;i++){
        int qr = wq0 + i*16 + g*4;
#pragma unroll
        for (int kb=0;kb<4;kb++){
          int kpos = k0 + kb*16 + l15;
#pragma unroll
          for (int r=0;r<4;r++)
            if (kpos == qr + r) s[i][kb][r] -= 1e9f*LOG2E;
        }
      }
    }

#pragma unroll
    for (int i=0;i<2;i++)
#pragma unroll
      for (int kb=0;kb<4;kb++)
#pragma unroll
        for (int r=0;r<4;r++){
          float p = exp2f(s[i][kb][r] + mb[kb]);
          lrun[i][r] += p;
          pw[(i*16 + g*4 + r)*PSTR + kb*16 + l15] = f2bf(p);
        }

    bf16x8 pa[2][2];
#pragma unroll
    for (int i=0;i<2;i++)
#pragma unroll
      for (int kk=0;kk<2;kk++)
        pa[i][kk] = *(const bf16x8*)&pw[(i*16 + l15)*PSTR + kk*32 + g*8];

#pragma unroll
    for (int kk=0;kk<2;kk++){
      int cs = ((kk<<2) + g) ^ (l15 & 7);
      bf16x8 vf[4];
#pragma unroll
      for (int dj=0;dj<4;dj++)
        vf[dj] = *(const bf16x8*)&VTs[buf][(dj*16 + l15)*64 + (cs<<3)];
#pragma unroll
      for (int i=0;i<2;i++)
#pragma unroll
        for (int dj=0;dj<4;dj++)
          ctxf[i][dj] = __builtin_amdgcn_mfma_f32_16x16x32_bf16(pa[i][kk], vf[dj], ctxf[i][dj], 0,0,0);
    }
  }
#undef STAGE

  float inv[2][4];
#pragma unroll
  for (int i=0;i<2;i++)
#pragma unroll
    for (int r=0;r<4;r++){
      float l = lrun[i][r];
      l += __shfl_xor(l, 1, 16);
      l += __shfl_xor(l, 2, 16);
      l += __shfl_xor(l, 4, 16);
      l += __shfl_xor(l, 8, 16);
      inv[i][r] = 1.0f / l;
    }
#pragma unroll
  for (int i=0;i<2;i++)
#pragma unroll
    for (int dj=0;dj<4;dj++)
#pragma unroll
      for (int r=0;r<4;r++)
        pw[(i*16 + g*4 + r)*64 + dj*16 + l15] = f2bf(ctxf[i][dj][r] * inv[i][r]);
#pragma unroll
  for (int t=0;t<4;t++){
    int row = lane >> 1, c = ((lane & 1)<<5) + t*8;
    const u16* pv = &pw[row*64 + c];
    u16x4 o8;
#pragma unroll
    for (int e=0;e<4;e++) o8[e] = pk_fp8(bf2f(pv[2*e]), bf2f(pv[2*e+1]));
    *(u16x4*)&CTX8[(rowbase + wq0 + row)*EE + h*DD + c] = o8;
  }
}

// ---------------------------------------------------------------------------
// K5: LayerNorm(AO + HU)*g + b + HT -> out (f32). HU/HT read as fp8.
// ---------------------------------------------------------------------------
__global__ __launch_bounds__(192,1) void ln_out_kernel(
    const u16* __restrict__ AO, const u8* __restrict__ HU8,
    const u8* __restrict__ HT8, const float* __restrict__ g,
    const float* __restrict__ bta, float* __restrict__ out)
{
  __shared__ float red[3];
  int r = blockIdx.x, tid = threadIdx.x;
  size_t base = (size_t)r*EE;
  int e0 = tid*4;
  u16x4 ao = *(const u16x4*)&AO[base+e0];
  int hu4 = *(const int*)&HU8[base+e0];
  int ht4 = *(const int*)&HT8[base+e0];
  f32x2 hulo = __builtin_amdgcn_cvt_pk_f32_fp8(hu4, false);
  f32x2 huhi = __builtin_amdgcn_cvt_pk_f32_fp8(hu4, true);
  f32x2 htlo = __builtin_amdgcn_cvt_pk_f32_fp8(ht4, false);
  f32x2 hthi = __builtin_amdgcn_cvt_pk_f32_fp8(ht4, true);
  float huv[4] = {hulo[0], hulo[1], huhi[0], huhi[1]};
  float htv[4] = {htlo[0], htlo[1], hthi[0], hthi[1]};
  float x[4];
#pragma unroll
  for (int j=0;j<4;j++) x[j] = bf2f(ao[j]) + huv[j];

  float s = x[0]+x[1]+x[2]+x[3];
#pragma unroll
  for (int o=32;o;o>>=1) s += __shfl_xor(s, o, 64);
  int w = tid>>6;
  if ((tid&63)==0) red[w] = s;
  __syncthreads();
  float mu = (red[0]+red[1]+red[2]) * (1.0f/EE);
  __syncthreads();
  float d2 = 0.f;
#pragma unroll
  for (int j=0;j<4;j++){ float d = x[j]-mu; d2 += d*d; }
#pragma unroll
  for (int o=32;o;o>>=1) d2 += __shfl_xor(d2, o, 64);
  if ((tid&63)==0) red[w] = d2;
  __syncthreads();
  float var = (red[0]+red[1]+red[2]) * (1.0f/EE);
  float rs = rsqrtf(var + 1e-12f);
  float4 gg = *(const float4*)&g[e0];
  float4 bb = *(const float4*)&bta[e0];
  float4 o4;
  o4.x = (x[0]-mu)*rs*gg.x + bb.x + htv[0];
  o4.y = (x[1]-mu)*rs*gg.y + bb.y + htv[1];
  o4.z = (x[2]-mu)*rs*gg.z + bb.z + htv[2];
  o4.w = (x[3]-mu)*rs*gg.w + bb.w + htv[3];
  *(float4*)&out[base+e0] = o4;
}

// ---------------------------------------------------------------------------
extern "C" void kernel_launch(void* const* d_in, const int* in_sizes, int n_in,
                              void* d_out, int out_size, void* d_ws, size_t ws_size,
                              hipStream_t stream)
{
  (void)in_sizes; (void)n_in; (void)out_size; (void)ws_size;
  const float* X    = (const float*)d_in[0];
  const float* mask = (const float*)d_in[1];
  const float* TE   = (const float*)d_in[2];
  const float* tp   = (const float*)d_in[3];
  const float* Wq   = (const float*)d_in[4];
  const float* bq   = (const float*)d_in[5];
  const float* Wk   = (const float*)d_in[6];
  const float* bk   = (const float*)d_in[7];
  const float* Wv   = (const float*)d_in[8];
  const float* bv   = (const float*)d_in[9];
  const float* Wo   = (const float*)d_in[10];
  const float* bo   = (const float*)d_in[11];
  const float* ln_g = (const float*)d_in[12];
  const float* ln_b = (const float*)d_in[13];

  float* out    = (float*)d_out;
  float* scores = out + BTE;

  char* p = (char*)d_ws;
  u8*  HT8  = (u8*)p;  p += BTE;                 // fp8 [8192][768]
  u8*  HU8  = (u8*)p;  p += BTE;
  u8*  CTX8 = (u8*)p;  p += BTE;
  u8*  WT8  = (u8*)p;  p += (size_t)4*EE*EE;     // fp8 4x[768][768] transposed
  u16* Qb   = (u16*)p; p += BTE*2;               // bf16
  u16* Kb   = (u16*)p; p += BTE*2;
  u16* VTb  = (u16*)p; p += BTE*2;               // bf16 [bh*64+d][512]
  u16* AOb  = (u16*)p; p += BTE*2;
  u16* ATT  = (u16*)p; p += (size_t)BT*128*2;    // bf16 [8192][128]
  u16* TEb  = (u16*)p; p += (size_t)128*EE*2;
  u16* TEt  = (u16*)p; p += (size_t)EE*128*2;
  float* MBg = (float*)p;

  prep_all_kernel<<<dim3(992), dim3(256), 0, stream>>>(
      Wq, Wk, Wv, Wo, WT8, TE, TEb, TEt, mask, MBg);

  label_scores_kernel<<<dim3(BT/16), dim3(64), 0, stream>>>(X, TEb, scores, ATT);

  // fle GEMM + fused fp8 HT/HU epilogue: M=8192, N=768, K=128
  gemm_fle_kernel<<<dim3((BT/128)*(EE/128)), dim3(256), 0, stream>>>(
      ATT, TEt, X, tp, HT8, HU8, EE, 128);

  // fused QKV projections (fp8 inputs, bf16 outputs): 64 m x 18 n
  gemm8_kernel<18,1><<<dim3(64*18), dim3(256), 0, stream>>>(
      HU8, HT8, WT8, bq, bk, bv, Qb, Kb, VTb);

  attn_mfma_kernel<<<dim3(BB*HH*4), dim3(256), 0, stream>>>(Qb, Kb, VTb, MBg, CTX8);

  // O projection (fp8 inputs): 64 x 6
  gemm8_kernel<6,0><<<dim3(64*6), dim3(256), 0, stream>>>(
      CTX8, nullptr, WT8 + 3*(size_t)EE*EE, bo, nullptr, nullptr, AOb, nullptr, nullptr);

  ln_out_kernel<<<dim3(BT), dim3(192), 0, stream>>>(AOb, HU8, HT8, ln_g, ln_b, out);
}

// Round 20
// 113.170 us; speedup vs baseline: 1.2510x; 1.0128x over previous
//
#include <hip/hip_runtime.h>

typedef unsigned char u8;
typedef unsigned short u16;
typedef u16 u16x4 __attribute__((ext_vector_type(4)));
typedef u16 u16x8 __attribute__((ext_vector_type(8)));
typedef __bf16 bf16x8 __attribute__((ext_vector_type(8)));
typedef float f32x2 __attribute__((ext_vector_type(2)));
typedef float f32x4 __attribute__((ext_vector_type(4)));
typedef long longx2 __attribute__((ext_vector_type(2)));

#define BB 16
#define TT 512
#define EE 768
#define HH 12
#define DD 64
#define LL 100
#define BT (BB*TT)             /* 8192 */
#define BTE ((size_t)BT*EE)    /* 6291456 */
#define LOG2E 1.44269504f
#define QSCALE (0.125f*LOG2E)  /* 1/sqrt(D)*log2e, folded into Q projection */
#define FIXMAX 44.0f           /* fixed softmax shift (log2 domain) */
#define PSTR 72                /* Pl row stride: 144B = 16B-aligned (b128 pa reads) */

__device__ __forceinline__ float bf2f(u16 u){
  union { float f; unsigned int i; } v; v.i = ((unsigned int)u) << 16; return v.f;
}
__device__ __forceinline__ u16 f2bf(float f){
  __bf16 h = (__bf16)f;
  union { __bf16 h; u16 u; } v; v.h = h; return v.u;
}
// fp8 e4m3 (OCP on gfx950) pack/unpack via HW cvt
__device__ __forceinline__ u16 pk_fp8(float a, float b){
  return (u16)(__builtin_amdgcn_cvt_pk_fp8_f32(a, b, 0, false) & 0xffff);
}
__device__ __forceinline__ u8 f2fp8(float a){
  return (u8)(__builtin_amdgcn_cvt_pk_fp8_f32(a, 0.f, 0, false) & 0xff);
}

// async 16B global->LDS DMA. LDS dest = wave-uniform base + lane*16.
__device__ __forceinline__ void gload16(const void* g, void* l){
  __builtin_amdgcn_global_load_lds(
      (const __attribute__((address_space(1))) void*)g,
      (__attribute__((address_space(3))) void*)l, 16, 0, 0);
}

// ---------------------------------------------------------------------------
// Merged prep: blocks 0-575 transpose+cast W[4] into FP8 [N][K];
// blocks 576-959 build TEb[128][768] / TEt[768][128] bf16; 960-991 mask bias.
// ---------------------------------------------------------------------------
__global__ __launch_bounds__(256,1) void prep_all_kernel(
    const float* __restrict__ Wq, const float* __restrict__ Wk,
    const float* __restrict__ Wv, const float* __restrict__ Wo,
    u8* __restrict__ WT8,
    const float* __restrict__ TE, u16* __restrict__ TEb, u16* __restrict__ TEt,
    const float* __restrict__ mask, float* __restrict__ MBg)
{
  __shared__ float tile[64][65];
  int bx = blockIdx.x;
  int tid = threadIdx.x;
  if (bx < 576){
    int m  = bx / 144, t = bx % 144;
    int tr = t / 12,  tc = t % 12;
    const float* W = (m==0)?Wq : (m==1)?Wk : (m==2)?Wv : Wo;
    u8* dst = WT8 + (size_t)m * EE * EE;
#pragma unroll
    for (int i=0;i<16;i++){
      int idx = tid + 256*i; int r = idx>>6, c = idx&63;
      tile[r][c] = W[(size_t)(tr*64+r)*EE + tc*64 + c];
    }
    __syncthreads();
#pragma unroll
    for (int i=0;i<8;i++){
      int idx = tid + 256*i;
      int r = idx >> 5, cp = idx & 31;
      u16 pk = pk_fp8(tile[cp*2][r], tile[cp*2+1][r]);
      *(u16*)&dst[(size_t)(tc*64+r)*EE + tr*64 + cp*2] = pk;
    }
  } else if (bx < 960){
    int e = (bx - 576)*2 + (tid >> 7);
    int c = tid & 127;
    u16 v = 0;
    if (c < LL) v = f2bf(TE[(size_t)c*EE + e]);
    TEt[(size_t)e*128 + c] = v;
    if (e < 128){
#pragma unroll
      for (int k=c; k<EE; k+=128)
        TEb[(size_t)e*EE + k] = (e < LL) ? f2bf(TE[(size_t)e*EE + k]) : (u16)0;
    }
  } else {
    int i = (bx - 960)*256 + tid;
    MBg[i] = (1.0f - mask[i]) * (-1e9f * LOG2E) - FIXMAX;
  }
}

// ---------------------------------------------------------------------------
// K1 v2: label scores + softmax, LDS-free (unchanged).
// ---------------------------------------------------------------------------
__global__ __launch_bounds__(64) void label_scores_kernel(
    const float* __restrict__ X, const u16* __restrict__ TEb,
    float* __restrict__ scores_out, u16* __restrict__ att)
{
  int m0 = blockIdx.x * 16;
  int lane = threadIdx.x;
  int l15 = lane & 15, g = lane >> 4;

  const float* xrow = X + (size_t)(m0 + l15)*EE;
  f32x4 s[7] = {};
  for (int k0=0; k0<EE; k0+=64){
    bf16x8 af[2];
#pragma unroll
    for (int kk=0;kk<2;kk++){
      const float* src = xrow + k0 + kk*32 + g*8;
      float4 a = *(const float4*)src, b = *(const float4*)(src+4);
      bf16x8 o;
      o[0]=(__bf16)a.x; o[1]=(__bf16)a.y; o[2]=(__bf16)a.z; o[3]=(__bf16)a.w;
      o[4]=(__bf16)b.x; o[5]=(__bf16)b.y; o[6]=(__bf16)b.z; o[7]=(__bf16)b.w;
      af[kk] = o;
    }
#pragma unroll
    for (int nt=0;nt<7;nt++){
      bf16x8 b0 = *(const bf16x8*)&TEb[(size_t)(nt*16+l15)*EE + k0 + g*8];
      bf16x8 b1 = *(const bf16x8*)&TEb[(size_t)(nt*16+l15)*EE + k0 + 32 + g*8];
      s[nt] = __builtin_amdgcn_mfma_f32_16x16x32_bf16(af[0], b0, s[nt], 0,0,0);
      s[nt] = __builtin_amdgcn_mfma_f32_16x16x32_bf16(af[1], b1, s[nt], 0,0,0);
    }
  }

  int rowb = m0 + g*4;
#pragma unroll
  for (int nt=0;nt<7;nt++){
    int col = nt*16 + l15;
    if (col < LL){
#pragma unroll
      for (int r=0;r<4;r++)
        scores_out[(size_t)(rowb + r)*LL + col] = s[nt][r];
    }
  }
  if (l15 >= 4){
#pragma unroll
    for (int r=0;r<4;r++) s[6][r] = -1e30f;
  }
  float inv[4];
#pragma unroll
  for (int r=0;r<4;r++){
    float tm = s[0][r];
#pragma unroll
    for (int nt=1;nt<7;nt++) tm = fmaxf(tm, s[nt][r]);
    tm = fmaxf(tm, __shfl_xor(tm, 1, 16));
    tm = fmaxf(tm, __shfl_xor(tm, 2, 16));
    tm = fmaxf(tm, __shfl_xor(tm, 4, 16));
    tm = fmaxf(tm, __shfl_xor(tm, 8, 16));
    float ps = 0.f;
#pragma unroll
    for (int nt=0;nt<7;nt++){
      float p = exp2f((s[nt][r] - tm) * LOG2E);
      s[nt][r] = p; ps += p;
    }
    ps += __shfl_xor(ps, 1, 16);
    ps += __shfl_xor(ps, 2, 16);
    ps += __shfl_xor(ps, 4, 16);
    ps += __shfl_xor(ps, 8, 16);
    inv[r] = 1.f/ps;
  }
#pragma unroll
  for (int nt=0;nt<7;nt++){
    int col = nt*16 + l15;
#pragma unroll
    for (int r=0;r<4;r++)
      att[(size_t)(rowb + r)*128 + col] = f2bf(s[nt][r] * inv[r]);
  }
  {
    int col = 112 + l15;
#pragma unroll
    for (int r=0;r<4;r++) att[(size_t)(rowb + r)*128 + col] = 0;
  }
}

// ---------------------------------------------------------------------------
// fle GEMM (bf16 interior, K=128): HT8 = fp8(X+acc), HU8 = fp8(X+tp).
// ---------------------------------------------------------------------------
__global__ __launch_bounds__(256,1) void gemm_fle_kernel(
    const u16* __restrict__ A, const u16* __restrict__ BTw,
    const float* __restrict__ Xf, const float* __restrict__ tp,
    u8* __restrict__ HT8, u8* __restrict__ HU8, int N, int K)
{
  __shared__ u16 As[128*40];
  __shared__ u16 Bs[128*40];
  int nb = N >> 7;
  int m0 = (blockIdx.x / nb) << 7;
  int n0 = (blockIdx.x % nb) << 7;
  int tid  = threadIdx.x, lane = tid & 63, w = tid >> 6;
  int wm = (w >> 1) << 6, wn = (w & 1) << 6;
  int lr = lane & 15, lk = (lane >> 4) << 3;

  f32x4 acc[4][4] = {};

  for (int k0 = 0; k0 < K; k0 += 32){
    __syncthreads();
#pragma unroll
    for (int i=0;i<2;i++){
      int idx = tid + (i<<8);
      int row = idx >> 2, kq = (idx & 3) << 3;
      *(u16x8*)&As[row*40 + kq] = *(const u16x8*)&A  [(size_t)(m0+row)*K + k0 + kq];
      *(u16x8*)&Bs[row*40 + kq] = *(const u16x8*)&BTw[(size_t)(n0+row)*K + k0 + kq];
    }
    __syncthreads();
    bf16x8 af[4], bfr[4];
#pragma unroll
    for (int i=0;i<4;i++) af [i] = *(const bf16x8*)&As[(wm + i*16 + lr)*40 + lk];
#pragma unroll
    for (int j=0;j<4;j++) bfr[j] = *(const bf16x8*)&Bs[(wn + j*16 + lr)*40 + lk];
#pragma unroll
    for (int i=0;i<4;i++)
#pragma unroll
      for (int j=0;j<4;j++)
        acc[i][j] = __builtin_amdgcn_mfma_f32_16x16x32_bf16(af[i], bfr[j], acc[i][j], 0, 0, 0);
  }

  int rbase = (lane >> 4) << 2;
#pragma unroll
  for (int j=0;j<4;j++){
    int col = n0 + wn + j*16 + lr;
    float tpv = tp[col];
#pragma unroll
    for (int i=0;i<4;i++){
#pragma unroll
      for (int r=0;r<4;r++){
        int row = m0 + wm + i*16 + rbase + r;
        float x = Xf[(size_t)row*EE + col];
        HT8[(size_t)row*EE + col] = f2fp8(x + acc[i][j][r]);
        HU8[(size_t)row*EE + col] = f2fp8(x + tpv);
      }
    }
  }
}

// ---------------------------------------------------------------------------
// gemm8 v5: FP8 projection GEMM. Frozen R13 k-loop + LDS-staged epilogue.
// NEW: Q/K outputs written FP8 (halves write bytes; attn consumes fp8 QK).
// V stays bf16 transposed; O-projection output stays bf16.
// ---------------------------------------------------------------------------
template<int NB, int FUSED>
__global__ __launch_bounds__(256,2) void gemm8_kernel(
    const u8* __restrict__ A0, const u8* __restrict__ A1,
    const u8* __restrict__ Wb,
    const float* __restrict__ b0, const float* __restrict__ b1,
    const float* __restrict__ b2,
    void* C0v, void* C1v, void* C2v)
{
  __shared__ __align__(16) u8 smem[33792];   // max(As+Bs=32KB, Cs=33792B)
  u8* As = smem;
  u8* Bs = smem + 16384;
  u16* Cs = (u16*)smem;                      // [128][132] bf16
  const int K = EE;

  int nwg = gridDim.x;
  int bid = blockIdx.x;
  int cpx = nwg >> 3;
  int swz = (bid & 7) * cpx + (bid >> 3);
  int mb = swz / NB, nb = swz % NB;
  int m0 = mb << 7;
  int n0 = (FUSED ? (nb % 6) : nb) << 7;

  int which = FUSED ? (nb / 6) : 0;
  const u8* Ap; const u8* Wp; const float* bp;
  if (!FUSED){ Ap = A0; Wp = Wb; bp = b0; }
  else {
    if (which == 0){ Ap = A0; Wp = Wb;                      bp = b0; }
    else if (which == 1){ Ap = A1; Wp = Wb + (size_t)EE*EE; bp = b1; }
    else { Ap = A1; Wp = Wb + 2*(size_t)EE*EE;              bp = b2; }
  }

  int tid = threadIdx.x, lane = tid & 63, w = tid >> 6;
  int wm = (w >> 1) << 6, wn = (w & 1) << 6;
  int lr = lane & 15, g = lane >> 4;
  int lrow = lane >> 3;
  int lchunk = (lane & 7) ^ lrow;          // source pre-swizzle (rule #21)

  f32x4 acc[4][4] = {};

  for (int k0 = 0; k0 < K; k0 += 128){
    __syncthreads();
#pragma unroll
    for (int t=0;t<4;t++){
      int r0 = w*32 + t*8;
      gload16(&Ap[(size_t)(m0 + r0 + lrow)*K + k0 + (lchunk<<4)], &As[r0*128]);
      gload16(&Wp[(size_t)(n0 + r0 + lrow)*K + k0 + (lchunk<<4)], &Bs[r0*128]);
    }
    __syncthreads();
#pragma unroll
    for (int t=0;t<2;t++){
      int cs = ((t<<2) + g) ^ (lr & 7);    // 16B chunk; zero-conflict pattern
      longx2 af[4], bfr[4];
#pragma unroll
      for (int i=0;i<4;i++) af [i] = *(const longx2*)&As[(wm + i*16 + lr)*128 + (cs<<4)];
#pragma unroll
      for (int j=0;j<4;j++) bfr[j] = *(const longx2*)&Bs[(wn + j*16 + lr)*128 + (cs<<4)];
#pragma unroll
      for (int i=0;i<4;i++)
#pragma unroll
        for (int j=0;j<4;j++){
          acc[i][j] = __builtin_amdgcn_mfma_f32_16x16x32_fp8_fp8(af[i][0], bfr[j][0], acc[i][j], 0, 0, 0);
          acc[i][j] = __builtin_amdgcn_mfma_f32_16x16x32_fp8_fp8(af[i][1], bfr[j][1], acc[i][j], 0, 0, 0);
        }
    }
  }

  // ---- epilogue via LDS: Cs[row][col], stride 132 ----
  int rbase = (lane >> 4) << 2;
  float scq = (FUSED && which==0) ? QSCALE : 1.0f;
  __syncthreads();
#pragma unroll
  for (int j=0;j<4;j++){
    int col = wn + j*16 + lr;
    float bv = bp[n0 + col];
#pragma unroll
    for (int i=0;i<4;i++)
#pragma unroll
      for (int r=0;r<4;r++)
        Cs[(wm + i*16 + rbase + r)*132 + col] = f2bf((acc[i][j][r] + bv) * scq);
  }
  __syncthreads();

  if (FUSED && which == 2){
    // V transposed bf16: 4 lanes cover 64B contiguous t.
    u16* Cp = (u16*)C2v;
    int bb = m0 >> 9, t0 = m0 & 511;
    int colb = tid >> 2;
    int tq = (tid & 3) << 3;
#pragma unroll
    for (int c2=0;c2<2;c2++){
      int col = colb + (c2<<6);
      int hh = (n0 + col) >> 6, d = (n0 + col) & 63;
      u16* dst = &Cp[((size_t)(bb*HH + hh)*DD + d)*TT + t0];
#pragma unroll
      for (int s=0;s<4;s++){
        int tt = tq + (s<<5);
        u16x8 v;
#pragma unroll
        for (int e=0;e<8;e++) v[e] = Cs[(tt+e)*132 + col];
        *(u16x8*)&dst[tt] = v;
      }
    }
  } else if (FUSED){
    // Q/K row-major FP8: 8 bf16 -> 4 fp8-pairs, 8B store, quad = 32B runs.
    u8* Cp8 = (u8*)(which==0 ? C0v : C1v);
#pragma unroll
    for (int p=0;p<2;p++){
      int row = (tid >> 2) + (p<<6);
      int c0 = (tid & 3) << 3;
      size_t gbase = (size_t)(m0 + row)*EE + n0;
      const u16* src = &Cs[row*132];
#pragma unroll
      for (int s=0;s<4;s++){
        int c = c0 + (s<<5);
        u16x4 lo = *(const u16x4*)&src[c];
        u16x4 hi = *(const u16x4*)&src[c+4];
        u16x4 o8;
        o8[0] = pk_fp8(bf2f(lo[0]), bf2f(lo[1]));
        o8[1] = pk_fp8(bf2f(lo[2]), bf2f(lo[3]));
        o8[2] = pk_fp8(bf2f(hi[0]), bf2f(hi[1]));
        o8[3] = pk_fp8(bf2f(hi[2]), bf2f(hi[3]));
        *(u16x4*)&Cp8[gbase + c] = o8;
      }
    }
  } else {
    // O-projection bf16 row-major: 4 lanes x 16B = 64B contiguous per quad.
    u16* Cp = (u16*)C0v;
#pragma unroll
    for (int p=0;p<2;p++){
      int row = (tid >> 2) + (p<<6);
      int c0 = (tid & 3) << 3;
      size_t gbase = (size_t)(m0 + row)*EE + n0;
      const u16* src = &Cs[row*132];
#pragma unroll
      for (int s=0;s<4;s++){
        int c = c0 + (s<<5);
        u16x4 lo = *(const u16x4*)&src[c];
        u16x4 hi = *(const u16x4*)&src[c+4];
        u16x8 v;
#pragma unroll
        for (int e=0;e<4;e++){ v[e] = lo[e]; v[e+4] = hi[e]; }
        *(u16x8*)&Cp[gbase + c] = v;
      }
    }
  }
}

// ---------------------------------------------------------------------------
// K4: MFMA flash attention v7 — R16 structure (dbuf STAGE, mb-before-STAGE,
// launch_bounds(256,3), PSTR=72), NOW with FP8 Q/K for the QK^T path:
//  - K staged fp8: 1 gload16/wave/tile (was 2); source pre-swizzle
//    chunk=(lane&3)^((row>>1)&3) (16B granular, DMA-compatible).
//  - kf: ds_read_b64 at slot8=(4kk+g)^(((l15>>1)&3)<<1) -> (l15 mod 8)
//    distinct 8B slots per quarter = 2-way = free. d = 32kk+8g+e (identity
//    mapping, Q side natural).
//  - S-MFMA: 16x16x32_fp8_fp8 (C/D layout dtype-independent; softmax/mask
//    code unchanged). P stays bf16 (fixed-max P spans 2^-61..2^-27 — fp8
//    would flush to zero). V/PV path unchanged bf16.
// ---------------------------------------------------------------------------
__global__ __launch_bounds__(256,3) void attn_mfma_kernel(
    const u8* __restrict__ Q8, const u8* __restrict__ K8,
    const u16* __restrict__ VT, const float* __restrict__ MBg,
    u8* __restrict__ CTX8)
{
  __shared__ __align__(16) u8 Ks[2][64*64];   // fp8 [row][64B]
  __shared__ u16 VTs[2][64*64];
  __shared__ u16 Pl [4][32*PSTR];

  int bx = blockIdx.x;
  int bh = bx % (BB*HH), q0 = (bx / (BB*HH)) << 7;
  int b = bh / HH, h = bh % HH;
  int tid = threadIdx.x, lane = tid & 63, w = tid >> 6;
  int l15 = lane & 15, g = lane >> 4;
  int wq0 = q0 + w*32;
  size_t rowbase = (size_t)b*TT;
  u16* pw = &Pl[w][0];
  const u8*  Kbh = K8 + rowbase*EE + h*DD;
  const u16* Vbh = VT + (size_t)bh*DD*TT;
  int lrow = lane >> 3, lchunk = (lane & 7) ^ (lane >> 3);   // V stage (bf16)
  int krow = lane >> 2;                                      // K stage (fp8)
  int kchunk = (lane & 3) ^ ((lane >> 3) & 3);               // = (lane&3)^((krow>>1)&3)

  long qf8[2][2];
#pragma unroll
  for (int i=0;i<2;i++)
#pragma unroll
    for (int kk=0;kk<2;kk++)
      qf8[i][kk] = *(const long*)&Q8[(rowbase + wq0 + i*16 + l15)*EE + h*DD + kk*32 + g*8];

  f32x4 ctxf[2][4] = {};
  float lrun[2][4] = {};

#define STAGE(buf, k0)                                                          \
  { gload16(&Kbh[(size_t)((k0) + w*16 + krow)*EE + (kchunk<<4)],                \
            &Ks[buf][(w*16)*64]);                                               \
    _Pragma("unroll")                                                           \
    for (int it=0; it<2; ++it){                                                 \
      int r0 = w*16 + it*8;                                                     \
      gload16(&Vbh[(size_t)(r0 + lrow)*TT + (k0) + (lchunk<<3)], &VTs[buf][r0*64]); } }

  STAGE(0, 0);

  for (int kt=0; kt<8; ++kt){
    int k0 = kt << 6;
    int buf = kt & 1;
    __syncthreads();

    // mb loads FIRST (older than stage loads -> counted vmcnt wait)
    float mb[4];
#pragma unroll
    for (int kb=0;kb<4;kb++) mb[kb] = MBg[rowbase + k0 + kb*16 + l15];

    if (kt < 7) STAGE(buf^1, k0+64);

    // ---- S = Q K^T (fp8 x fp8; log2e domain, Q pre-scaled) ----
    f32x4 s[2][4] = {};
    int f8 = ((l15 >> 1) & 3) << 1;
#pragma unroll
    for (int kk=0;kk<2;kk++){
      long kop[4];
#pragma unroll
      for (int kb=0;kb<4;kb++){
        int R = kb*16 + l15;
        int slot8 = ((kk<<2) + g) ^ f8;
        kop[kb] = *(const long*)&Ks[buf][R*64 + (slot8<<3)];
      }
#pragma unroll
      for (int i=0;i<2;i++)
#pragma unroll
        for (int kb=0;kb<4;kb++)
          s[i][kb] = __builtin_amdgcn_mfma_f32_16x16x32_fp8_fp8(qf8[i][kk], kop[kb], s[i][kb], 0,0,0);
    }

    // ---- diag mask ----
    if ((k0 < wq0 + 32) && (k0 + 64 > wq0)){
#pragma unroll
      for (int i=0;i<2;i++){
        int qr = wq0 + i*16 + g*4;
#pragma unroll
        for (int kb=0;kb<4;kb++){
          int kpos = k0 + kb*16 + l15;
#pragma unroll
          for (int r=0;r<4;r++)
            if (kpos == qr + r) s[i][kb][r] -= 1e9f*LOG2E;
        }
      }
    }

    // ---- p = exp2(s + mb); lane-local sum; P -> LDS (A-frag layout) ----
#pragma unroll
    for (int i=0;i<2;i++)
#pragma unroll
      for (int kb=0;kb<4;kb++)
#pragma unroll
        for (int r=0;r<4;r++){
          float p = exp2f(s[i][kb][r] + mb[kb]);
          lrun[i][r] += p;
          pw[(i*16 + g*4 + r)*PSTR + kb*16 + l15] = f2bf(p);
        }

    bf16x8 pa[2][2];
#pragma unroll
    for (int i=0;i<2;i++)
#pragma unroll
      for (int kk=0;kk<2;kk++)
        pa[i][kk] = *(const bf16x8*)&pw[(i*16 + l15)*PSTR + kk*32 + g*8];

    // ---- ctx += P V (bf16) ----
#pragma unroll
    for (int kk=0;kk<2;kk++){
      int cs = ((kk<<2) + g) ^ (l15 & 7);
      bf16x8 vf[4];
#pragma unroll
      for (int dj=0;dj<4;dj++)
        vf[dj] = *(const bf16x8*)&VTs[buf][(dj*16 + l15)*64 + (cs<<3)];
#pragma unroll
      for (int i=0;i<2;i++)
#pragma unroll
        for (int dj=0;dj<4;dj++)
          ctxf[i][dj] = __builtin_amdgcn_mfma_f32_16x16x32_bf16(pa[i][kk], vf[dj], ctxf[i][dj], 0,0,0);
    }
  }
#undef STAGE

  float inv[2][4];
#pragma unroll
  for (int i=0;i<2;i++)
#pragma unroll
    for (int r=0;r<4;r++){
      float l = lrun[i][r];
      l += __shfl_xor(l, 1, 16);
      l += __shfl_xor(l, 2, 16);
      l += __shfl_xor(l, 4, 16);
      l += __shfl_xor(l, 8, 16);
      inv[i][r] = 1.0f / l;
    }
#pragma unroll
  for (int i=0;i<2;i++)
#pragma unroll
    for (int dj=0;dj<4;dj++)
#pragma unroll
      for (int r=0;r<4;r++)
        pw[(i*16 + g*4 + r)*64 + dj*16 + l15] = f2bf(ctxf[i][dj][r] * inv[i][r]);
#pragma unroll
  for (int t=0;t<4;t++){
    int row = lane >> 1, c = ((lane & 1)<<5) + t*8;
    const u16* pv = &pw[row*64 + c];
    u16x4 o8;
#pragma unroll
    for (int e=0;e<4;e++) o8[e] = pk_fp8(bf2f(pv[2*e]), bf2f(pv[2*e+1]));
    *(u16x4*)&CTX8[(rowbase + wq0 + row)*EE + h*DD + c] = o8;
  }
}

// ---------------------------------------------------------------------------
// K5: LayerNorm(AO + HU)*g + b + HT -> out (f32). HU/HT read as fp8.
// ---------------------------------------------------------------------------
__global__ __launch_bounds__(192,1) void ln_out_kernel(
    const u16* __restrict__ AO, const u8* __restrict__ HU8,
    const u8* __restrict__ HT8, const float* __restrict__ g,
    const float* __restrict__ bta, float* __restrict__ out)
{
  __shared__ float red[3];
  int r = blockIdx.x, tid = threadIdx.x;
  size_t base = (size_t)r*EE;
  int e0 = tid*4;
  u16x4 ao = *(const u16x4*)&AO[base+e0];
  int hu4 = *(const int*)&HU8[base+e0];
  int ht4 = *(const int*)&HT8[base+e0];
  f32x2 hulo = __builtin_amdgcn_cvt_pk_f32_fp8(hu4, false);
  f32x2 huhi = __builtin_amdgcn_cvt_pk_f32_fp8(hu4, true);
  f32x2 htlo = __builtin_amdgcn_cvt_pk_f32_fp8(ht4, false);
  f32x2 hthi = __builtin_amdgcn_cvt_pk_f32_fp8(ht4, true);
  float huv[4] = {hulo[0], hulo[1], huhi[0], huhi[1]};
  float htv[4] = {htlo[0], htlo[1], hthi[0], hthi[1]};
  float x[4];
#pragma unroll
  for (int j=0;j<4;j++) x[j] = bf2f(ao[j]) + huv[j];

  float s = x[0]+x[1]+x[2]+x[3];
#pragma unroll
  for (int o=32;o;o>>=1) s += __shfl_xor(s, o, 64);
  int w = tid>>6;
  if ((tid&63)==0) red[w] = s;
  __syncthreads();
  float mu = (red[0]+red[1]+red[2]) * (1.0f/EE);
  __syncthreads();
  float d2 = 0.f;
#pragma unroll
  for (int j=0;j<4;j++){ float d = x[j]-mu; d2 += d*d; }
#pragma unroll
  for (int o=32;o;o>>=1) d2 += __shfl_xor(d2, o, 64);
  if ((tid&63)==0) red[w] = d2;
  __syncthreads();
  float var = (red[0]+red[1]+red[2]) * (1.0f/EE);
  float rs = rsqrtf(var + 1e-12f);
  float4 gg = *(const float4*)&g[e0];
  float4 bb = *(const float4*)&bta[e0];
  float4 o4;
  o4.x = (x[0]-mu)*rs*gg.x + bb.x + htv[0];
  o4.y = (x[1]-mu)*rs*gg.y + bb.y + htv[1];
  o4.z = (x[2]-mu)*rs*gg.z + bb.z + htv[2];
  o4.w = (x[3]-mu)*rs*gg.w + bb.w + htv[3];
  *(float4*)&out[base+e0] = o4;
}

// ---------------------------------------------------------------------------
extern "C" void kernel_launch(void* const* d_in, const int* in_sizes, int n_in,
                              void* d_out, int out_size, void* d_ws, size_t ws_size,
                              hipStream_t stream)
{
  (void)in_sizes; (void)n_in; (void)out_size; (void)ws_size;
  const float* X    = (const float*)d_in[0];
  const float* mask = (const float*)d_in[1];
  const float* TE   = (const float*)d_in[2];
  const float* tp   = (const float*)d_in[3];
  const float* Wq   = (const float*)d_in[4];
  const float* bq   = (const float*)d_in[5];
  const float* Wk   = (const float*)d_in[6];
  const float* bk   = (const float*)d_in[7];
  const float* Wv   = (const float*)d_in[8];
  const float* bv   = (const float*)d_in[9];
  const float* Wo   = (const float*)d_in[10];
  const float* bo   = (const float*)d_in[11];
  const float* ln_g = (const float*)d_in[12];
  const float* ln_b = (const float*)d_in[13];

  float* out    = (float*)d_out;
  float* scores = out + BTE;

  char* p = (char*)d_ws;
  u8*  HT8  = (u8*)p;  p += BTE;                 // fp8 [8192][768]
  u8*  HU8  = (u8*)p;  p += BTE;
  u8*  CTX8 = (u8*)p;  p += BTE;
  u8*  WT8  = (u8*)p;  p += (size_t)4*EE*EE;     // fp8 4x[768][768] transposed
  u8*  Qb8  = (u8*)p;  p += BTE;                 // fp8 Q (pre-scaled)
  u8*  Kb8  = (u8*)p;  p += BTE;                 // fp8 K
  u16* VTb  = (u16*)p; p += BTE*2;               // bf16 [bh*64+d][512]
  u16* AOb  = (u16*)p; p += BTE*2;
  u16* ATT  = (u16*)p; p += (size_t)BT*128*2;    // bf16 [8192][128]
  u16* TEb  = (u16*)p; p += (size_t)128*EE*2;
  u16* TEt  = (u16*)p; p += (size_t)EE*128*2;
  float* MBg = (float*)p;

  prep_all_kernel<<<dim3(992), dim3(256), 0, stream>>>(
      Wq, Wk, Wv, Wo, WT8, TE, TEb, TEt, mask, MBg);

  label_scores_kernel<<<dim3(BT/16), dim3(64), 0, stream>>>(X, TEb, scores, ATT);

  // fle GEMM + fused fp8 HT/HU epilogue: M=8192, N=768, K=128
  gemm_fle_kernel<<<dim3((BT/128)*(EE/128)), dim3(256), 0, stream>>>(
      ATT, TEt, X, tp, HT8, HU8, EE, 128);

  // fused QKV projections (fp8 in; Q/K out fp8, V out bf16-T): 64 m x 18 n
  gemm8_kernel<18,1><<<dim3(64*18), dim3(256), 0, stream>>>(
      HU8, HT8, WT8, bq, bk, bv, (void*)Qb8, (void*)Kb8, (void*)VTb);

  attn_mfma_kernel<<<dim3(BB*HH*4), dim3(256), 0, stream>>>(Qb8, Kb8, VTb, MBg, CTX8);

  // O projection (fp8 inputs, bf16 output): 64 x 6
  gemm8_kernel<6,0><<<dim3(64*6), dim3(256), 0, stream>>>(
      CTX8, nullptr, WT8 + 3*(size_t)EE*EE, bo, nullptr, nullptr,
      (void*)AOb, nullptr, nullptr);

  ln_out_kernel<<<dim3(BT), dim3(192), 0, stream>>>(AOb, HU8, HT8, ln_g, ln_b, out);
}